// Round 4
// baseline (723.255 us; speedup 1.0000x reference)
//
#include <hip/hip_runtime.h>

#define Bn 4
#define Cn 256
#define C8 32
#define Hn 64
#define Wn 64
#define HWn 4096
#define PADR 66
#define ROWS (HWn + 2 * PADR)   // 4228 padded pixel-rows per batch
#define MARGIN 6e-3f

typedef __bf16 bf16x8 __attribute__((ext_vector_type(8)));
typedef float floatx4 __attribute__((ext_vector_type(4)));
typedef unsigned short u16x8 __attribute__((ext_vector_type(8)));

__device__ __forceinline__ unsigned short f2bf(float f) {
  union { float f; unsigned int u; } c; c.f = f;
  unsigned int u = c.u;
  return (unsigned short)((u + 0x7FFFu + ((u >> 16) & 1u)) >> 16);  // RNE
}
__device__ __forceinline__ float bf2f(unsigned short h) {
  union { unsigned int u; float f; } c; c.u = ((unsigned int)h) << 16;
  return c.f;
}
__device__ __forceinline__ void gl_lds16(const void* g, void* l) {
  __builtin_amdgcn_global_load_lds(
      (__attribute__((address_space(1))) void*)(uintptr_t)g,
      (__attribute__((address_space(3))) void*)(uintptr_t)l, 16, 0, 0);
}

// ---------------------------------------------------------------------------
// K0: weight prep + zero the flagged-query counter.
// ---------------------------------------------------------------------------
__global__ void prep_w(const float* __restrict__ Wq, const float* __restrict__ bq,
                       const float* __restrict__ Wk, const float* __restrict__ bk,
                       const float* __restrict__ Wv, const float* __restrict__ Wf,
                       double* __restrict__ Wqt, double* __restrict__ bqd,
                       double* __restrict__ Wkt, double* __restrict__ bkd,
                       float* __restrict__ Wvt, unsigned short* __restrict__ Wfb,
                       int* __restrict__ cnt) {
  size_t t = (size_t)blockIdx.x * 256 + threadIdx.x;
  if (t == 0) cnt[0] = 0;
  if (t < 8192) {
    int o = (int)(t / 256), c = (int)(t % 256);
    Wqt[(size_t)c * 32 + o] = (double)Wq[t];
    Wkt[(size_t)c * 32 + o] = (double)Wk[t];
  }
  if (t < 32) { bqd[t] = (double)bq[t]; bkd[t] = (double)bk[t]; }
  if (t < 65536) {
    int o = (int)(t / 256), c = (int)(t % 256);
    Wvt[(size_t)c * 256 + o] = Wv[t];
  }
  if (t < (size_t)9 * 256 * 512) {
    int tap = (int)(t / (256 * 512));
    int rem = (int)(t % (256 * 512));
    int o = rem / 512, ci = rem % 512;
    Wfb[t] = f2bf(Wf[((size_t)o * 512 + ci) * 9 + tap]);
  }
}

// ---------------------------------------------------------------------------
// K1: q/k projection in fp64 + bf16 hi/lo split outputs (unchanged).
// ---------------------------------------------------------------------------
__global__ __launch_bounds__(256) void proj_qk(
    const float* __restrict__ cross_x, const float* __restrict__ front_x,
    const double* __restrict__ Wqt, const double* __restrict__ bqd,
    const double* __restrict__ Wkt, const double* __restrict__ bkd,
    double* __restrict__ qd, double* __restrict__ kd,
    unsigned short* __restrict__ qhi, unsigned short* __restrict__ qlo,
    unsigned short* __restrict__ khi, unsigned short* __restrict__ klo) {
  int j = blockIdx.x * 256 + threadIdx.x;
  int b = blockIdx.y;
  int z = blockIdx.z;
  const float* x = (z == 0) ? cross_x : front_x;
  const double* Wt = (z == 0) ? Wqt : Wkt;
  const double* bd = (z == 0) ? bqd : bkd;
  double* outp = (z == 0) ? qd : kd;
  unsigned short* hip_ = (z == 0) ? qhi : khi;
  unsigned short* lop_ = (z == 0) ? qlo : klo;

  const float* xb = x + (size_t)b * Cn * HWn + j;
  double acc[C8];
#pragma unroll
  for (int o = 0; o < C8; ++o) acc[o] = bd[o];
  for (int c = 0; c < Cn; ++c) {
    double xv = (double)xb[(size_t)c * HWn];
    const double* wrow = Wt + (size_t)c * C8;
#pragma unroll
    for (int o = 0; o < C8; ++o) acc[o] += wrow[o] * xv;
  }
  double* op = outp + ((size_t)b * HWn + j) * C8;
  unsigned short* hp = hip_ + ((size_t)b * HWn + j) * C8;
  unsigned short* lp = lop_ + ((size_t)b * HWn + j) * C8;
#pragma unroll
  for (int o = 0; o < C8; ++o) {
    op[o] = acc[o];
    float f = (float)acc[o];
    unsigned short h = f2bf(f);
    hp[o] = h;
    lp[o] = f2bf(f - bf2f(h));
  }
}

// ---------------------------------------------------------------------------
// K2: approximate energy via split-bf16 MFMA, LDS-free (A-frags straight from
// global, all L2-hot), fused max/top-2/argmax + flagged-query compaction.
// 3 independent MFMA accumulators per 16-row group to break the dep chain.
// ---------------------------------------------------------------------------
__global__ __launch_bounds__(256) void energy_approx(
    const unsigned short* __restrict__ khi, const unsigned short* __restrict__ klo,
    const unsigned short* __restrict__ qhi, const unsigned short* __restrict__ qlo,
    float* __restrict__ star, int* __restrict__ argb,
    int* __restrict__ cnt, int* __restrict__ list) {
  int b = blockIdx.y;
  int j0 = blockIdx.x * 64;
  int tid = threadIdx.x;
  int lane = tid & 63, wv = tid >> 6;
  int lm = lane & 15, lq = lane >> 4;

  int j = j0 + wv * 16 + lm;
  bf16x8 qh = *reinterpret_cast<const bf16x8*>(qhi + ((size_t)b * HWn + j) * 32 + lq * 8);
  bf16x8 ql = *reinterpret_cast<const bf16x8*>(qlo + ((size_t)b * HWn + j) * 32 + lq * 8);

  const unsigned short* kh_base = khi + (size_t)b * HWn * 32 + lq * 8;
  const unsigned short* kl_base = klo + (size_t)b * HWn * 32 + lq * 8;

  float b1 = -3.0e38f, b2 = -3.0e38f;
  int i1 = 0;

#pragma unroll 4
  for (int i0 = 0; i0 < HWn; i0 += 16) {
    bf16x8 ah = *reinterpret_cast<const bf16x8*>(kh_base + (size_t)(i0 + lm) * 32);
    bf16x8 al = *reinterpret_cast<const bf16x8*>(kl_base + (size_t)(i0 + lm) * 32);
    floatx4 ahh = (floatx4)0.0f, ahl = (floatx4)0.0f, alh = (floatx4)0.0f;
    ahh = __builtin_amdgcn_mfma_f32_16x16x32_bf16(ah, qh, ahh, 0, 0, 0);
    ahl = __builtin_amdgcn_mfma_f32_16x16x32_bf16(ah, ql, ahl, 0, 0, 0);
    alh = __builtin_amdgcn_mfma_f32_16x16x32_bf16(al, qh, alh, 0, 0, 0);
    floatx4 e = ahh + ahl + alh;
    float m4 = fmaxf(fmaxf(e[0], e[1]), fmaxf(e[2], e[3]));
    if (m4 > b1) {  // rare after warm-up: exact top-2 maintenance
      int ib = i0 + lq * 4;
#pragma unroll
      for (int r = 0; r < 4; ++r) {
        float s = e[r];
        if (s > b1) { b2 = b1; b1 = s; i1 = ib + r; }
        else b2 = fmaxf(b2, s);
      }
    } else {
      b2 = fmaxf(b2, m4);
    }
  }
  // merge the 4 quads holding the same j (lanes lm, lm+16, lm+32, lm+48)
#pragma unroll
  for (int m = 16; m <= 32; m <<= 1) {
    float ob1 = __shfl_xor(b1, m, 64);
    int oi1 = __shfl_xor(i1, m, 64);
    float ob2 = __shfl_xor(b2, m, 64);
    float c2;
    if (ob1 > b1 || (ob1 == b1 && oi1 < i1)) {
      c2 = fmaxf(b1, ob2);
      b1 = ob1; i1 = oi1;
    } else {
      c2 = fmaxf(ob1, b2);
    }
    b2 = c2;
  }
  if (lq == 0) {
    size_t o = (size_t)b * HWn + j;
    star[o] = b1;
    argb[o] = i1;
    if (b1 - b2 < MARGIN) {
      int slot = atomicAdd(cnt, 1);
      list[slot] = (b << 12) | j;
    }
  }
}

// ---------------------------------------------------------------------------
// K3: exact fp64 recheck over the compacted flagged list. One BLOCK per
// query (256 lanes -> 16 i-iterations), block-stride over the list.
// ---------------------------------------------------------------------------
__global__ __launch_bounds__(256) void recheck(
    const double* __restrict__ qd, const double* __restrict__ kd,
    const int* __restrict__ cnt, const int* __restrict__ list,
    float* __restrict__ star, int* __restrict__ argb) {
  __shared__ double bvS[4];
  __shared__ int biS[4];
  int n = cnt[0];
  int tid = threadIdx.x;
  int lane = tid & 63, wv = tid >> 6;
  for (int idx = blockIdx.x; idx < n; idx += gridDim.x) {
    int e = list[idx];
    int b = e >> 12, j = e & 4095;
    const double* qp = qd + ((size_t)b * HWn + j) * 32;
    double qj[32];
#pragma unroll
    for (int o = 0; o < 32; ++o) qj[o] = qp[o];
    double best = -1.0e300;
    int bi = 1 << 30;
    for (int i = tid; i < HWn; i += 256) {
      const double* kp = kd + ((size_t)b * HWn + i) * 32;
      double s = 0.0;
#pragma unroll
      for (int o = 0; o < 32; ++o) s += kp[o] * qj[o];
      if (s > best) { best = s; bi = i; }
    }
#pragma unroll
    for (int m = 1; m < 64; m <<= 1) {
      double ob = __shfl_xor(best, m, 64);
      int oi = __shfl_xor(bi, m, 64);
      if (ob > best || (ob == best && oi < bi)) { best = ob; bi = oi; }
    }
    if (lane == 0) { bvS[wv] = best; biS[wv] = bi; }
    __syncthreads();
    if (tid == 0) {
#pragma unroll
      for (int w = 1; w < 4; ++w) {
        if (bvS[w] > best || (bvS[w] == best && biS[w] < bi)) {
          best = bvS[w]; bi = biS[w];
        }
      }
      star[(size_t)b * HWn + j] = (float)best;
      argb[(size_t)b * HWn + j] = bi;
    }
    __syncthreads();
  }
}

// ---------------------------------------------------------------------------
// K4: v projection fp32, PIXEL-MAJOR output v[b][hw][c] (for coalesced
// per-query gather). Per-thread float4 stores are line-complete per block.
// ---------------------------------------------------------------------------
__global__ __launch_bounds__(256) void proj_v(
    const float* __restrict__ x, const float* __restrict__ Wvt,
    const float* __restrict__ bv, float* __restrict__ v) {
  int j = blockIdx.x * 256 + threadIdx.x;
  int b = blockIdx.y;
  int o0 = blockIdx.z * 64;
  const float* xb = x + (size_t)b * Cn * HWn + j;
  float acc[64];
#pragma unroll
  for (int o = 0; o < 64; ++o) acc[o] = bv[o0 + o];
  for (int c = 0; c < Cn; ++c) {
    float xv = xb[(size_t)c * HWn];
    const float* wrow = Wvt + (size_t)c * 256 + o0;
#pragma unroll
    for (int o = 0; o < 64; ++o) acc[o] += wrow[o] * xv;
  }
  float* vp = v + ((size_t)b * HWn + j) * 256 + o0;
#pragma unroll
  for (int o = 0; o < 64; o += 4) {
    floatx4 w4 = {acc[o], acc[o + 1], acc[o + 2], acc[o + 3]};
    *reinterpret_cast<floatx4*>(vp + o) = w4;
  }
}

// ---------------------------------------------------------------------------
// K5: transpose front_x -> catC[b][row][0..256) bf16 pixel-major (unchanged).
// ---------------------------------------------------------------------------
__global__ __launch_bounds__(256) void cat_fx(
    const float* __restrict__ fx, unsigned short* __restrict__ catC) {
  int j0 = blockIdx.x * 64;
  int ci0 = blockIdx.y * 64;
  int b = blockIdx.z;
  int tid = threadIdx.x;
  __shared__ unsigned short tile[64][66];

  for (int u = tid; u < 4096; u += 256) {
    int cl = u >> 6, hw_l = u & 63;
    tile[cl][hw_l] = f2bf(fx[((size_t)(b * Cn + ci0 + cl)) * HWn + j0 + hw_l]);
  }
  __syncthreads();
  for (int u = tid; u < 4096; u += 256) {
    int hw_l = u >> 6, cl = u & 63;
    catC[((size_t)b * ROWS + PADR + j0 + hw_l) * 512 + ci0 + cl] = tile[cl][hw_l];
  }
}

// ---------------------------------------------------------------------------
// K6: gather into catC upper channels (now contiguous 1KB reads from
// pixel-major v) + zero pad rows.
// ---------------------------------------------------------------------------
__global__ __launch_bounds__(256) void gather_cat(
    const float* __restrict__ v, const int* __restrict__ argb,
    unsigned short* __restrict__ catC) {
  int b = blockIdx.y;
  int tid = threadIdx.x;
  if (blockIdx.x == 16) {
    for (int u = tid; u < 2 * PADR * 512; u += 256) {
      int r = u >> 9;
      int rr = (r < PADR) ? r : (HWn + r);
      catC[((size_t)b * ROWS + rr) * 512 + (u & 511)] = 0;
    }
    return;
  }
  int j = blockIdx.x * 256 + tid;
  int aj = argb[(size_t)b * HWn + j];
  const float* vrow = v + ((size_t)b * HWn + aj) * 256;
  unsigned short* dst = catC + ((size_t)b * ROWS + PADR + j) * 512 + 256;
#pragma unroll 4
  for (int c = 0; c < 256; c += 8) {
    floatx4 x0 = *reinterpret_cast<const floatx4*>(vrow + c);
    floatx4 x1 = *reinterpret_cast<const floatx4*>(vrow + c + 4);
    u16x8 pk;
    pk[0] = f2bf(x0[0]); pk[1] = f2bf(x0[1]); pk[2] = f2bf(x0[2]); pk[3] = f2bf(x0[3]);
    pk[4] = f2bf(x1[0]); pk[5] = f2bf(x1[1]); pk[6] = f2bf(x1[2]); pk[7] = f2bf(x1[3]);
    *reinterpret_cast<u16x8*>(dst + c) = pk;
  }
}

// ---------------------------------------------------------------------------
// K7: conv3x3 implicit GEMM on MFMA bf16 + epilogue (unchanged: 128x128 tile).
// ---------------------------------------------------------------------------
__global__ __launch_bounds__(256) void conv_mfma(
    const unsigned short* __restrict__ catC, const unsigned short* __restrict__ Wfb,
    const float* __restrict__ bf, const float* __restrict__ star,
    const float* __restrict__ fx, float* __restrict__ out) {
  int m0 = blockIdx.x * 128;   // pixel tile
  int o0 = blockIdx.y * 128;   // output-channel tile
  int b = blockIdx.z;
  int tid = threadIdx.x;
  int lane = tid & 63;
  int wv = tid >> 6;
  int wm = wv >> 1;            // o half
  int wn = wv & 1;             // pix half
  int lm = lane & 15, lq = lane >> 4;
  const bool lane_first = (lm == 0);
  const bool lane_last = (lm == 15);

  __shared__ __align__(16) unsigned short AS[128 * 32];   // [o][k]   8 KB
  __shared__ __align__(16) unsigned short BS[128 * 32];   // [pix][k] 8 KB

  floatx4 acc[4][4];
#pragma unroll
  for (int im = 0; im < 4; ++im)
#pragma unroll
    for (int in = 0; in < 4; ++in) acc[im][in] = (floatx4)0.0f;

  const int srow = lane >> 2, soff = (lane & 3) * 8;

  for (int tap = 0; tap < 9; ++tap) {
    int dy = tap / 3 - 1, dx = tap % 3 - 1;
    const unsigned short* bg =
        catC + ((size_t)b * ROWS + PADR + m0 + dy * 64 + dx) * 512;
    const unsigned short* ag = Wfb + ((size_t)tap * 256 + o0) * 512;
    int killsel = dx;

    for (int kc = 0; kc < 512; kc += 32) {
      __syncthreads();
#pragma unroll
      for (int i = 0; i < 2; ++i) {
        int r0 = wv * 32 + i * 16;
        gl_lds16(ag + ((size_t)(r0 + srow)) * 512 + kc + soff, &AS[r0 * 32]);
        gl_lds16(bg + ((size_t)(r0 + srow)) * 512 + kc + soff, &BS[r0 * 32]);
      }
      __syncthreads();

      bf16x8 afr[4];
#pragma unroll
      for (int im = 0; im < 4; ++im)
        afr[im] = *reinterpret_cast<const bf16x8*>(
            &AS[(wm * 64 + im * 16 + lm) * 32 + lq * 8]);

#pragma unroll
      for (int in = 0; in < 4; ++in) {
        u16x8 braw = *reinterpret_cast<const u16x8*>(
            &BS[(wn * 64 + in * 16 + lm) * 32 + lq * 8]);
        if ((killsel == -1 && in == 0 && lane_first) ||
            (killsel == 1 && in == 3 && lane_last))
          braw = (u16x8)(unsigned short)0;
        union { u16x8 u; bf16x8 h; } cvt; cvt.u = braw;
#pragma unroll
        for (int im = 0; im < 4; ++im)
          acc[im][in] = __builtin_amdgcn_mfma_f32_16x16x32_bf16(
              afr[im], cvt.h, acc[im][in], 0, 0, 0);
      }
    }
  }

#pragma unroll
  for (int in = 0; in < 4; ++in) {
    int p = m0 + wn * 64 + in * 16 + lm;
    float Sp = star[(size_t)b * HWn + p];
#pragma unroll
    for (int im = 0; im < 4; ++im) {
      int ob = o0 + wm * 64 + im * 16 + lq * 4;
#pragma unroll
      for (int r = 0; r < 4; ++r) {
        int o = ob + r;
        size_t idx = ((size_t)(b * Cn + o)) * HWn + p;
        out[idx] = fx[idx] + (acc[im][in][r] + bf[o]) * Sp;
      }
    }
  }
}

// ---------------------------------------------------------------------------
extern "C" void kernel_launch(void* const* d_in, const int* in_sizes, int n_in,
                              void* d_out, int out_size, void* d_ws, size_t ws_size,
                              hipStream_t stream) {
  const float* front_x   = (const float*)d_in[0];
  const float* cross_x   = (const float*)d_in[1];
  const float* front_hat = (const float*)d_in[2];
  const float* Wq = (const float*)d_in[3];
  const float* bq = (const float*)d_in[4];
  const float* Wk = (const float*)d_in[5];
  const float* bk = (const float*)d_in[6];
  const float* Wv = (const float*)d_in[7];
  const float* bv = (const float*)d_in[8];
  const float* Wf = (const float*)d_in[9];
  const float* bf = (const float*)d_in[10];
  float* out = (float*)d_out;

  char* ws = (char*)d_ws;
  size_t off = 0;
  auto alloc = [&](size_t bytes) -> void* {
    void* p = (void*)(ws + off);
    off += (bytes + 255) & ~(size_t)255;
    return p;
  };
  double* Wqt = (double*)alloc(8192 * sizeof(double));
  double* Wkt = (double*)alloc(8192 * sizeof(double));
  double* bqd = (double*)alloc(32 * sizeof(double));
  double* bkd = (double*)alloc(32 * sizeof(double));
  float*  Wvt = (float*)alloc(65536 * sizeof(float));
  unsigned short* Wfb = (unsigned short*)alloc((size_t)9 * 256 * 512 * sizeof(unsigned short));
  double* qd  = (double*)alloc((size_t)Bn * HWn * C8 * sizeof(double));
  double* kd  = (double*)alloc((size_t)Bn * HWn * C8 * sizeof(double));
  unsigned short* qhi = (unsigned short*)alloc((size_t)Bn * HWn * C8 * 2);
  unsigned short* qlo = (unsigned short*)alloc((size_t)Bn * HWn * C8 * 2);
  unsigned short* khi = (unsigned short*)alloc((size_t)Bn * HWn * C8 * 2);
  unsigned short* klo = (unsigned short*)alloc((size_t)Bn * HWn * C8 * 2);
  float*  star = (float*)alloc((size_t)Bn * HWn * sizeof(float));
  int*    argb = (int*)alloc((size_t)Bn * HWn * sizeof(int));
  int*    cnt  = (int*)alloc(256);
  int*    list = (int*)alloc((size_t)Bn * HWn * sizeof(int));
  float*  v    = (float*)alloc((size_t)Bn * Cn * HWn * sizeof(float));
  unsigned short* catC = (unsigned short*)alloc((size_t)Bn * ROWS * 512 * sizeof(unsigned short));

  prep_w<<<dim3((9 * 256 * 512 + 255) / 256), dim3(256), 0, stream>>>(
      Wq, bq, Wk, bk, Wv, Wf, Wqt, bqd, Wkt, bkd, Wvt, Wfb, cnt);

  proj_qk<<<dim3(HWn / 256, Bn, 2), dim3(256), 0, stream>>>(
      cross_x, front_x, Wqt, bqd, Wkt, bkd, qd, kd, qhi, qlo, khi, klo);

  energy_approx<<<dim3(HWn / 64, Bn), dim3(256), 0, stream>>>(
      khi, klo, qhi, qlo, star, argb, cnt, list);

  recheck<<<dim3(256), dim3(256), 0, stream>>>(qd, kd, cnt, list, star, argb);

  proj_v<<<dim3(HWn / 256, Bn, 4), dim3(256), 0, stream>>>(front_hat, Wvt, bv, v);

  cat_fx<<<dim3(HWn / 64, Cn / 64, Bn), dim3(256), 0, stream>>>(front_x, catC);

  gather_cat<<<dim3(HWn / 256 + 1, Bn), dim3(256), 0, stream>>>(v, argb, catC);

  conv_mfma<<<dim3(HWn / 128, Cn / 128, Bn), dim3(256), 0, stream>>>(
      catC, Wfb, bf, star, front_x, out);
}

// Round 5
// 507.367 us; speedup vs baseline: 1.4255x; 1.4255x over previous
//
#include <hip/hip_runtime.h>

#define Bn 4
#define Cn 256
#define C8 32
#define Hn 64
#define Wn 64
#define HWn 4096
#define PADR 66
#define ROWS (HWn + 2 * PADR)   // 4228 padded pixel-rows per batch
#define MARGIN 6e-3f

typedef __bf16 bf16x8 __attribute__((ext_vector_type(8)));
typedef float floatx4 __attribute__((ext_vector_type(4)));
typedef unsigned short u16x8 __attribute__((ext_vector_type(8)));

__device__ __forceinline__ unsigned short f2bf(float f) {
  union { float f; unsigned int u; } c; c.f = f;
  unsigned int u = c.u;
  return (unsigned short)((u + 0x7FFFu + ((u >> 16) & 1u)) >> 16);  // RNE
}
__device__ __forceinline__ float bf2f(unsigned short h) {
  union { unsigned int u; float f; } c; c.u = ((unsigned int)h) << 16;
  return c.f;
}
__device__ __forceinline__ void gl_lds16(const void* g, void* l) {
  __builtin_amdgcn_global_load_lds(
      (__attribute__((address_space(1))) void*)(uintptr_t)g,
      (__attribute__((address_space(3))) void*)(uintptr_t)l, 16, 0, 0);
}

// ---------------------------------------------------------------------------
// K0: weight prep + zero flagged-query counter.
//   Wq/Wk -> fp64 [c][32]; Wv -> bf16 [o][c] (direct); Wf -> bf16 [tap][o][ci]
// ---------------------------------------------------------------------------
__global__ void prep_w(const float* __restrict__ Wq, const float* __restrict__ bq,
                       const float* __restrict__ Wk, const float* __restrict__ bk,
                       const float* __restrict__ Wv, const float* __restrict__ Wf,
                       double* __restrict__ Wqt, double* __restrict__ bqd,
                       double* __restrict__ Wkt, double* __restrict__ bkd,
                       unsigned short* __restrict__ Wvb, unsigned short* __restrict__ Wfb,
                       int* __restrict__ cnt) {
  size_t t = (size_t)blockIdx.x * 256 + threadIdx.x;
  if (t == 0) cnt[0] = 0;
  if (t < 8192) {
    int o = (int)(t / 256), c = (int)(t % 256);
    Wqt[(size_t)c * 32 + o] = (double)Wq[t];
    Wkt[(size_t)c * 32 + o] = (double)Wk[t];
  }
  if (t < 32) { bqd[t] = (double)bq[t]; bkd[t] = (double)bk[t]; }
  if (t < 65536) Wvb[t] = f2bf(Wv[t]);   // [o][c] row-major already
  if (t < (size_t)9 * 256 * 512) {
    int tap = (int)(t / (256 * 512));
    int rem = (int)(t % (256 * 512));
    int o = rem / 512, ci = rem % 512;
    Wfb[t] = f2bf(Wf[((size_t)o * 512 + ci) * 9 + tap]);
  }
}

// ---------------------------------------------------------------------------
// K1: q/k projection fp64, occupancy-fixed: wave = 64 j, each of the 4 waves
// in a block owns an 8-wide o-slice (wave-uniform 64B s_load per channel).
// Grid 64 x Bn x 2 -> 2048 waves (8/CU).
// ---------------------------------------------------------------------------
__global__ __launch_bounds__(256) void proj_qk(
    const float* __restrict__ cross_x, const float* __restrict__ front_x,
    const double* __restrict__ Wqt, const double* __restrict__ bqd,
    const double* __restrict__ Wkt, const double* __restrict__ bkd,
    double* __restrict__ qd, double* __restrict__ kd,
    unsigned short* __restrict__ qhi, unsigned short* __restrict__ qlo,
    unsigned short* __restrict__ khi, unsigned short* __restrict__ klo) {
  int tid = threadIdx.x;
  int lane = tid & 63, wv = tid >> 6;
  int j = blockIdx.x * 64 + lane;
  int b = blockIdx.y;
  int z = blockIdx.z;
  const float* x = (z == 0) ? cross_x : front_x;
  const double* Wt = (z == 0) ? Wqt : Wkt;
  const double* bd = (z == 0) ? bqd : bkd;
  double* outp = (z == 0) ? qd : kd;
  unsigned short* hip_ = (z == 0) ? qhi : khi;
  unsigned short* lop_ = (z == 0) ? qlo : klo;
  int o0 = wv * 8;

  const float* xb = x + (size_t)b * Cn * HWn + j;
  double acc[8];
#pragma unroll
  for (int o = 0; o < 8; ++o) acc[o] = bd[o0 + o];
#pragma unroll 4
  for (int c = 0; c < Cn; ++c) {
    double xv = (double)xb[(size_t)c * HWn];
    const double* wrow = Wt + (size_t)c * C8 + o0;  // wave-uniform 64B
#pragma unroll
    for (int o = 0; o < 8; ++o) acc[o] += wrow[o] * xv;
  }
  double* op = outp + ((size_t)b * HWn + j) * C8 + o0;
  u16x8 hv, lv;
#pragma unroll
  for (int o = 0; o < 8; ++o) {
    op[o] = acc[o];
    float f = (float)acc[o];
    unsigned short h = f2bf(f);
    hv[o] = h;
    lv[o] = f2bf(f - bf2f(h));
  }
  *reinterpret_cast<u16x8*>(hip_ + ((size_t)b * HWn + j) * C8 + o0) = hv;
  *reinterpret_cast<u16x8*>(lop_ + ((size_t)b * HWn + j) * C8 + o0) = lv;
}

// ---------------------------------------------------------------------------
// K2: approximate energy via split-bf16 MFMA (LDS-free), fused top-2/argmax,
// flagged-query compaction (unchanged).
// ---------------------------------------------------------------------------
__global__ __launch_bounds__(256) void energy_approx(
    const unsigned short* __restrict__ khi, const unsigned short* __restrict__ klo,
    const unsigned short* __restrict__ qhi, const unsigned short* __restrict__ qlo,
    float* __restrict__ star, int* __restrict__ argb,
    int* __restrict__ cnt, int* __restrict__ list) {
  int b = blockIdx.y;
  int j0 = blockIdx.x * 64;
  int tid = threadIdx.x;
  int lane = tid & 63, wv = tid >> 6;
  int lm = lane & 15, lq = lane >> 4;

  int j = j0 + wv * 16 + lm;
  bf16x8 qh = *reinterpret_cast<const bf16x8*>(qhi + ((size_t)b * HWn + j) * 32 + lq * 8);
  bf16x8 ql = *reinterpret_cast<const bf16x8*>(qlo + ((size_t)b * HWn + j) * 32 + lq * 8);

  const unsigned short* kh_base = khi + (size_t)b * HWn * 32 + lq * 8;
  const unsigned short* kl_base = klo + (size_t)b * HWn * 32 + lq * 8;

  float b1 = -3.0e38f, b2 = -3.0e38f;
  int i1 = 0;

#pragma unroll 4
  for (int i0 = 0; i0 < HWn; i0 += 16) {
    bf16x8 ah = *reinterpret_cast<const bf16x8*>(kh_base + (size_t)(i0 + lm) * 32);
    bf16x8 al = *reinterpret_cast<const bf16x8*>(kl_base + (size_t)(i0 + lm) * 32);
    floatx4 ahh = (floatx4)0.0f, ahl = (floatx4)0.0f, alh = (floatx4)0.0f;
    ahh = __builtin_amdgcn_mfma_f32_16x16x32_bf16(ah, qh, ahh, 0, 0, 0);
    ahl = __builtin_amdgcn_mfma_f32_16x16x32_bf16(ah, ql, ahl, 0, 0, 0);
    alh = __builtin_amdgcn_mfma_f32_16x16x32_bf16(al, qh, alh, 0, 0, 0);
    floatx4 e = ahh + ahl + alh;
    float m4 = fmaxf(fmaxf(e[0], e[1]), fmaxf(e[2], e[3]));
    if (m4 > b1) {
      int ib = i0 + lq * 4;
#pragma unroll
      for (int r = 0; r < 4; ++r) {
        float s = e[r];
        if (s > b1) { b2 = b1; b1 = s; i1 = ib + r; }
        else b2 = fmaxf(b2, s);
      }
    } else {
      b2 = fmaxf(b2, m4);
    }
  }
#pragma unroll
  for (int m = 16; m <= 32; m <<= 1) {
    float ob1 = __shfl_xor(b1, m, 64);
    int oi1 = __shfl_xor(i1, m, 64);
    float ob2 = __shfl_xor(b2, m, 64);
    float c2;
    if (ob1 > b1 || (ob1 == b1 && oi1 < i1)) {
      c2 = fmaxf(b1, ob2);
      b1 = ob1; i1 = oi1;
    } else {
      c2 = fmaxf(ob1, b2);
    }
    b2 = c2;
  }
  if (lq == 0) {
    size_t o = (size_t)b * HWn + j;
    star[o] = b1;
    argb[o] = i1;
    if (b1 - b2 < MARGIN) {
      int slot = atomicAdd(cnt, 1);
      list[slot] = (b << 12) | j;
    }
  }
}

// ---------------------------------------------------------------------------
// K3: exact fp64 recheck over the compacted flagged list (unchanged).
// ---------------------------------------------------------------------------
__global__ __launch_bounds__(256) void recheck(
    const double* __restrict__ qd, const double* __restrict__ kd,
    const int* __restrict__ cnt, const int* __restrict__ list,
    float* __restrict__ star, int* __restrict__ argb) {
  __shared__ double bvS[4];
  __shared__ int biS[4];
  int n = cnt[0];
  int tid = threadIdx.x;
  int lane = tid & 63, wv = tid >> 6;
  for (int idx = blockIdx.x; idx < n; idx += gridDim.x) {
    int e = list[idx];
    int b = e >> 12, j = e & 4095;
    const double* qp = qd + ((size_t)b * HWn + j) * 32;
    double qj[32];
#pragma unroll
    for (int o = 0; o < 32; ++o) qj[o] = qp[o];
    double best = -1.0e300;
    int bi = 1 << 30;
    for (int i = tid; i < HWn; i += 256) {
      const double* kp = kd + ((size_t)b * HWn + i) * 32;
      double s = 0.0;
#pragma unroll
      for (int o = 0; o < 32; ++o) s += kp[o] * qj[o];
      if (s > best) { best = s; bi = i; }
    }
#pragma unroll
    for (int m = 1; m < 64; m <<= 1) {
      double ob = __shfl_xor(best, m, 64);
      int oi = __shfl_xor(bi, m, 64);
      if (ob > best || (ob == best && oi < bi)) { best = ob; bi = oi; }
    }
    if (lane == 0) { bvS[wv] = best; biS[wv] = bi; }
    __syncthreads();
    if (tid == 0) {
#pragma unroll
      for (int w = 1; w < 4; ++w) {
        if (bvS[w] > best || (bvS[w] == best && biS[w] < bi)) {
          best = bvS[w]; bi = biS[w];
        }
      }
      star[(size_t)b * HWn + j] = (float)best;
      argb[(size_t)b * HWn + j] = bi;
    }
    __syncthreads();
  }
}

// ---------------------------------------------------------------------------
// K4: transpose to bf16 pixel-major. z&1==0: front_x -> catC[...][0..256);
// z&1==1: front_x_hat -> xht[b][hw][256] (B-operand of the v-GEMM).
// ---------------------------------------------------------------------------
__global__ __launch_bounds__(256) void cat_fx(
    const float* __restrict__ fx, const float* __restrict__ fxh,
    unsigned short* __restrict__ catC, unsigned short* __restrict__ xht) {
  int j0 = blockIdx.x * 64;
  int ci0 = blockIdx.y * 64;
  int b = blockIdx.z >> 1;
  int which = blockIdx.z & 1;
  int tid = threadIdx.x;
  __shared__ unsigned short tile[64][66];

  const float* src = (which == 0) ? fx : fxh;
  for (int u = tid; u < 4096; u += 256) {
    int cl = u >> 6, hw_l = u & 63;
    tile[cl][hw_l] = f2bf(src[((size_t)(b * Cn + ci0 + cl)) * HWn + j0 + hw_l]);
  }
  __syncthreads();
  if (which == 0) {
    for (int u = tid; u < 4096; u += 256) {
      int hw_l = u >> 6, cl = u & 63;
      catC[((size_t)b * ROWS + PADR + j0 + hw_l) * 512 + ci0 + cl] = tile[cl][hw_l];
    }
  } else {
    for (int u = tid; u < 4096; u += 256) {
      int hw_l = u >> 6, cl = u & 63;
      xht[((size_t)b * HWn + j0 + hw_l) * 256 + ci0 + cl] = tile[cl][hw_l];
    }
  }
}

// ---------------------------------------------------------------------------
// K5: v projection as bf16 MFMA GEMM. A=Wvb[o][c], B=xht[pix][c], K=256.
// Block 128o x 128pix, wave 64x64 (4x4 frags). Epilogue: +bv, bf16, LDS
// transpose (pad 136 keeps 16B alignment, 272B rows) -> coalesced
// pixel-major stores vbf[b][pix][o].
// ---------------------------------------------------------------------------
__global__ __launch_bounds__(256) void proj_v_mfma(
    const unsigned short* __restrict__ xht, const unsigned short* __restrict__ Wvb,
    const float* __restrict__ bv, unsigned short* __restrict__ vbf) {
  int m0 = blockIdx.x * 128;   // pixel tile
  int o0 = blockIdx.y * 128;   // o tile
  int b = blockIdx.z;
  int tid = threadIdx.x;
  int lane = tid & 63, wv = tid >> 6;
  int wm = wv >> 1, wn = wv & 1;
  int lm = lane & 15, lq = lane >> 4;

  __shared__ __align__(16) unsigned short AS[128 * 32];
  __shared__ __align__(16) unsigned short BS[128 * 32];
  __shared__ __align__(16) unsigned short TS[128 * 136];

  floatx4 acc[4][4];
#pragma unroll
  for (int im = 0; im < 4; ++im)
#pragma unroll
    for (int in = 0; in < 4; ++in) acc[im][in] = (floatx4)0.0f;

  const int srow = lane >> 2, soff = (lane & 3) * 8;
  const unsigned short* ag = Wvb + (size_t)o0 * 256;
  const unsigned short* bg = xht + ((size_t)b * HWn + m0) * 256;

  for (int kc = 0; kc < 256; kc += 32) {
    __syncthreads();
#pragma unroll
    for (int i = 0; i < 2; ++i) {
      int r0 = wv * 32 + i * 16;
      gl_lds16(ag + ((size_t)(r0 + srow)) * 256 + kc + soff, &AS[r0 * 32]);
      gl_lds16(bg + ((size_t)(r0 + srow)) * 256 + kc + soff, &BS[r0 * 32]);
    }
    __syncthreads();

    bf16x8 afr[4];
#pragma unroll
    for (int im = 0; im < 4; ++im)
      afr[im] = *reinterpret_cast<const bf16x8*>(
          &AS[(wm * 64 + im * 16 + lm) * 32 + lq * 8]);
#pragma unroll
    for (int in = 0; in < 4; ++in) {
      bf16x8 bfr = *reinterpret_cast<const bf16x8*>(
          &BS[(wn * 64 + in * 16 + lm) * 32 + lq * 8]);
#pragma unroll
      for (int im = 0; im < 4; ++im)
        acc[im][in] = __builtin_amdgcn_mfma_f32_16x16x32_bf16(
            afr[im], bfr, acc[im][in], 0, 0, 0);
    }
  }

  // epilogue: +bias, bf16, transpose via LDS, coalesced store
  __syncthreads();
#pragma unroll
  for (int in = 0; in < 4; ++in) {
    int pl = wn * 64 + in * 16 + lm;
#pragma unroll
    for (int im = 0; im < 4; ++im) {
#pragma unroll
      for (int r = 0; r < 4; ++r) {
        int ol = wm * 64 + im * 16 + lq * 4 + r;
        TS[pl * 136 + ol] = f2bf(acc[im][in][r] + bv[o0 + ol]);
      }
    }
  }
  __syncthreads();
  for (int idx = tid; idx < 128 * 16; idx += 256) {
    int p = idx >> 4, ch = idx & 15;
    u16x8 val = *reinterpret_cast<const u16x8*>(&TS[p * 136 + ch * 8]);
    *reinterpret_cast<u16x8*>(
        &vbf[((size_t)b * HWn + m0 + p) * 256 + o0 + ch * 8]) = val;
  }
}

// ---------------------------------------------------------------------------
// K6: gather: catC[b][j][256..512) = vbf[b][arg[b,j]][*]. 32 lanes per pixel
// -> coalesced 512B copies. blockIdx.x==16 zeroes the pad rows.
// ---------------------------------------------------------------------------
__global__ __launch_bounds__(256) void gather_cat(
    const unsigned short* __restrict__ vbf, const int* __restrict__ argb,
    unsigned short* __restrict__ catC) {
  int b = blockIdx.y;
  int tid = threadIdx.x;
  if (blockIdx.x == 16) {
    for (int u = tid; u < 2 * PADR * 512; u += 256) {
      int r = u >> 9;
      int rr = (r < PADR) ? r : (HWn + r);
      catC[((size_t)b * ROWS + rr) * 512 + (u & 511)] = 0;
    }
    return;
  }
  __shared__ int ajS[256];
  int j0 = blockIdx.x * 256;
  ajS[tid] = argb[(size_t)b * HWn + j0 + tid];
  __syncthreads();
#pragma unroll 4
  for (int u = tid; u < 256 * 32; u += 256) {
    int pl = u >> 5, ch = u & 31;
    int aj = ajS[pl];
    u16x8 val = *reinterpret_cast<const u16x8*>(
        &vbf[((size_t)b * HWn + aj) * 256 + ch * 8]);
    *reinterpret_cast<u16x8*>(
        &catC[((size_t)b * ROWS + PADR + j0 + pl) * 512 + 256 + ch * 8]) = val;
  }
}

// ---------------------------------------------------------------------------
// K7: conv3x3 implicit GEMM on MFMA bf16 + epilogue (unchanged).
// ---------------------------------------------------------------------------
__global__ __launch_bounds__(256) void conv_mfma(
    const unsigned short* __restrict__ catC, const unsigned short* __restrict__ Wfb,
    const float* __restrict__ bf, const float* __restrict__ star,
    const float* __restrict__ fx, float* __restrict__ out) {
  int m0 = blockIdx.x * 128;
  int o0 = blockIdx.y * 128;
  int b = blockIdx.z;
  int tid = threadIdx.x;
  int lane = tid & 63;
  int wv = tid >> 6;
  int wm = wv >> 1;
  int wn = wv & 1;
  int lm = lane & 15, lq = lane >> 4;
  const bool lane_first = (lm == 0);
  const bool lane_last = (lm == 15);

  __shared__ __align__(16) unsigned short AS[128 * 32];
  __shared__ __align__(16) unsigned short BS[128 * 32];

  floatx4 acc[4][4];
#pragma unroll
  for (int im = 0; im < 4; ++im)
#pragma unroll
    for (int in = 0; in < 4; ++in) acc[im][in] = (floatx4)0.0f;

  const int srow = lane >> 2, soff = (lane & 3) * 8;

  for (int tap = 0; tap < 9; ++tap) {
    int dy = tap / 3 - 1, dx = tap % 3 - 1;
    const unsigned short* bg =
        catC + ((size_t)b * ROWS + PADR + m0 + dy * 64 + dx) * 512;
    const unsigned short* ag = Wfb + ((size_t)tap * 256 + o0) * 512;
    int killsel = dx;

    for (int kc = 0; kc < 512; kc += 32) {
      __syncthreads();
#pragma unroll
      for (int i = 0; i < 2; ++i) {
        int r0 = wv * 32 + i * 16;
        gl_lds16(ag + ((size_t)(r0 + srow)) * 512 + kc + soff, &AS[r0 * 32]);
        gl_lds16(bg + ((size_t)(r0 + srow)) * 512 + kc + soff, &BS[r0 * 32]);
      }
      __syncthreads();

      bf16x8 afr[4];
#pragma unroll
      for (int im = 0; im < 4; ++im)
        afr[im] = *reinterpret_cast<const bf16x8*>(
            &AS[(wm * 64 + im * 16 + lm) * 32 + lq * 8]);

#pragma unroll
      for (int in = 0; in < 4; ++in) {
        u16x8 braw = *reinterpret_cast<const u16x8*>(
            &BS[(wn * 64 + in * 16 + lm) * 32 + lq * 8]);
        if ((killsel == -1 && in == 0 && lane_first) ||
            (killsel == 1 && in == 3 && lane_last))
          braw = (u16x8)(unsigned short)0;
        union { u16x8 u; bf16x8 h; } cvt; cvt.u = braw;
#pragma unroll
        for (int im = 0; im < 4; ++im)
          acc[im][in] = __builtin_amdgcn_mfma_f32_16x16x32_bf16(
              afr[im], cvt.h, acc[im][in], 0, 0, 0);
      }
    }
  }

#pragma unroll
  for (int in = 0; in < 4; ++in) {
    int p = m0 + wn * 64 + in * 16 + lm;
    float Sp = star[(size_t)b * HWn + p];
#pragma unroll
    for (int im = 0; im < 4; ++im) {
      int ob = o0 + wm * 64 + im * 16 + lq * 4;
#pragma unroll
      for (int r = 0; r < 4; ++r) {
        int o = ob + r;
        size_t idx = ((size_t)(b * Cn + o)) * HWn + p;
        out[idx] = fx[idx] + (acc[im][in][r] + bf[o]) * Sp;
      }
    }
  }
}

// ---------------------------------------------------------------------------
extern "C" void kernel_launch(void* const* d_in, const int* in_sizes, int n_in,
                              void* d_out, int out_size, void* d_ws, size_t ws_size,
                              hipStream_t stream) {
  const float* front_x   = (const float*)d_in[0];
  const float* cross_x   = (const float*)d_in[1];
  const float* front_hat = (const float*)d_in[2];
  const float* Wq = (const float*)d_in[3];
  const float* bq = (const float*)d_in[4];
  const float* Wk = (const float*)d_in[5];
  const float* bk = (const float*)d_in[6];
  const float* Wv = (const float*)d_in[7];
  const float* bv = (const float*)d_in[8];
  const float* Wf = (const float*)d_in[9];
  const float* bf = (const float*)d_in[10];
  float* out = (float*)d_out;

  char* ws = (char*)d_ws;
  size_t off = 0;
  auto alloc = [&](size_t bytes) -> void* {
    void* p = (void*)(ws + off);
    off += (bytes + 255) & ~(size_t)255;
    return p;
  };
  double* Wqt = (double*)alloc(8192 * sizeof(double));
  double* Wkt = (double*)alloc(8192 * sizeof(double));
  double* bqd = (double*)alloc(32 * sizeof(double));
  double* bkd = (double*)alloc(32 * sizeof(double));
  unsigned short* Wvb = (unsigned short*)alloc(65536 * sizeof(unsigned short));
  unsigned short* Wfb = (unsigned short*)alloc((size_t)9 * 256 * 512 * sizeof(unsigned short));
  double* qd  = (double*)alloc((size_t)Bn * HWn * C8 * sizeof(double));
  double* kd  = (double*)alloc((size_t)Bn * HWn * C8 * sizeof(double));
  unsigned short* qhi = (unsigned short*)alloc((size_t)Bn * HWn * C8 * 2);
  unsigned short* qlo = (unsigned short*)alloc((size_t)Bn * HWn * C8 * 2);
  unsigned short* khi = (unsigned short*)alloc((size_t)Bn * HWn * C8 * 2);
  unsigned short* klo = (unsigned short*)alloc((size_t)Bn * HWn * C8 * 2);
  float*  star = (float*)alloc((size_t)Bn * HWn * sizeof(float));
  int*    argb = (int*)alloc((size_t)Bn * HWn * sizeof(int));
  int*    cnt  = (int*)alloc(256);
  int*    list = (int*)alloc((size_t)Bn * HWn * sizeof(int));
  unsigned short* xht = (unsigned short*)alloc((size_t)Bn * HWn * 256 * 2);
  unsigned short* vbf = (unsigned short*)alloc((size_t)Bn * HWn * 256 * 2);
  unsigned short* catC = (unsigned short*)alloc((size_t)Bn * ROWS * 512 * sizeof(unsigned short));

  prep_w<<<dim3((9 * 256 * 512 + 255) / 256), dim3(256), 0, stream>>>(
      Wq, bq, Wk, bk, Wv, Wf, Wqt, bqd, Wkt, bkd, Wvb, Wfb, cnt);

  proj_qk<<<dim3(HWn / 64, Bn, 2), dim3(256), 0, stream>>>(
      cross_x, front_x, Wqt, bqd, Wkt, bkd, qd, kd, qhi, qlo, khi, klo);

  energy_approx<<<dim3(HWn / 64, Bn), dim3(256), 0, stream>>>(
      khi, klo, qhi, qlo, star, argb, cnt, list);

  recheck<<<dim3(256), dim3(256), 0, stream>>>(qd, kd, cnt, list, star, argb);

  cat_fx<<<dim3(HWn / 64, Cn / 64, Bn * 2), dim3(256), 0, stream>>>(
      front_x, front_hat, catC, xht);

  proj_v_mfma<<<dim3(HWn / 128, Cn / 128, Bn), dim3(256), 0, stream>>>(
      xht, Wvb, bv, vbf);

  gather_cat<<<dim3(HWn / 256 + 1, Bn), dim3(256), 0, stream>>>(vbf, argb, catC);

  conv_mfma<<<dim3(HWn / 128, Cn / 128, Bn), dim3(256), 0, stream>>>(
      catC, Wfb, bf, star, front_x, out);
}

// Round 6
// 406.900 us; speedup vs baseline: 1.7775x; 1.2469x over previous
//
#include <hip/hip_runtime.h>

#define Bn 4
#define Cn 256
#define C8 32
#define Hn 64
#define Wn 64
#define HWn 4096
#define PADR 66
#define ROWS (HWn + 2 * PADR)   // 4228 padded pixel-rows per batch
#define MARGIN 6e-3f

typedef __bf16 bf16x8 __attribute__((ext_vector_type(8)));
typedef float floatx4 __attribute__((ext_vector_type(4)));
typedef unsigned short u16x8 __attribute__((ext_vector_type(8)));

__device__ __forceinline__ unsigned short f2bf(float f) {
  union { float f; unsigned int u; } c; c.f = f;
  unsigned int u = c.u;
  return (unsigned short)((u + 0x7FFFu + ((u >> 16) & 1u)) >> 16);  // RNE
}
__device__ __forceinline__ float bf2f(unsigned short h) {
  union { unsigned int u; float f; } c; c.u = ((unsigned int)h) << 16;
  return c.f;
}
__device__ __forceinline__ void gl_lds16(const void* g, void* l) {
  __builtin_amdgcn_global_load_lds(
      (__attribute__((address_space(1))) void*)(uintptr_t)g,
      (__attribute__((address_space(3))) void*)(uintptr_t)l, 16, 0, 0);
}

// ---------------------------------------------------------------------------
// K0: weight prep + zero flagged-query counter (unchanged).
// ---------------------------------------------------------------------------
__global__ void prep_w(const float* __restrict__ Wq, const float* __restrict__ bq,
                       const float* __restrict__ Wk, const float* __restrict__ bk,
                       const float* __restrict__ Wv, const float* __restrict__ Wf,
                       double* __restrict__ Wqt, double* __restrict__ bqd,
                       double* __restrict__ Wkt, double* __restrict__ bkd,
                       unsigned short* __restrict__ Wvb, unsigned short* __restrict__ Wfb,
                       int* __restrict__ cnt) {
  size_t t = (size_t)blockIdx.x * 256 + threadIdx.x;
  if (t == 0) cnt[0] = 0;
  if (t < 8192) {
    int o = (int)(t / 256), c = (int)(t % 256);
    Wqt[(size_t)c * 32 + o] = (double)Wq[t];
    Wkt[(size_t)c * 32 + o] = (double)Wk[t];
  }
  if (t < 32) { bqd[t] = (double)bq[t]; bkd[t] = (double)bk[t]; }
  if (t < 65536) Wvb[t] = f2bf(Wv[t]);   // [o][c] row-major already
  if (t < (size_t)9 * 256 * 512) {
    int tap = (int)(t / (256 * 512));
    int rem = (int)(t % (256 * 512));
    int o = rem / 512, ci = rem % 512;
    Wfb[t] = f2bf(Wf[((size_t)o * 512 + ci) * 9 + tap]);
  }
}

// ---------------------------------------------------------------------------
// K1: q/k projection fp64 (unchanged from R5).
// ---------------------------------------------------------------------------
__global__ __launch_bounds__(256) void proj_qk(
    const float* __restrict__ cross_x, const float* __restrict__ front_x,
    const double* __restrict__ Wqt, const double* __restrict__ bqd,
    const double* __restrict__ Wkt, const double* __restrict__ bkd,
    double* __restrict__ qd, double* __restrict__ kd,
    unsigned short* __restrict__ qhi, unsigned short* __restrict__ qlo,
    unsigned short* __restrict__ khi, unsigned short* __restrict__ klo) {
  int tid = threadIdx.x;
  int lane = tid & 63, wv = tid >> 6;
  int j = blockIdx.x * 64 + lane;
  int b = blockIdx.y;
  int z = blockIdx.z;
  const float* x = (z == 0) ? cross_x : front_x;
  const double* Wt = (z == 0) ? Wqt : Wkt;
  const double* bd = (z == 0) ? bqd : bkd;
  double* outp = (z == 0) ? qd : kd;
  unsigned short* hip_ = (z == 0) ? qhi : khi;
  unsigned short* lop_ = (z == 0) ? qlo : klo;
  int o0 = wv * 8;

  const float* xb = x + (size_t)b * Cn * HWn + j;
  double acc[8];
#pragma unroll
  for (int o = 0; o < 8; ++o) acc[o] = bd[o0 + o];
#pragma unroll 4
  for (int c = 0; c < Cn; ++c) {
    double xv = (double)xb[(size_t)c * HWn];
    const double* wrow = Wt + (size_t)c * C8 + o0;  // wave-uniform 64B
#pragma unroll
    for (int o = 0; o < 8; ++o) acc[o] += wrow[o] * xv;
  }
  double* op = outp + ((size_t)b * HWn + j) * C8 + o0;
  u16x8 hv, lv;
#pragma unroll
  for (int o = 0; o < 8; ++o) {
    op[o] = acc[o];
    float f = (float)acc[o];
    unsigned short h = f2bf(f);
    hv[o] = h;
    lv[o] = f2bf(f - bf2f(h));
  }
  *reinterpret_cast<u16x8*>(hip_ + ((size_t)b * HWn + j) * C8 + o0) = hv;
  *reinterpret_cast<u16x8*>(lop_ + ((size_t)b * HWn + j) * C8 + o0) = lv;
}

// ---------------------------------------------------------------------------
// K2: approximate energy via split-bf16 MFMA. Occupancy-fixed: 1024-thread
// blocks (16 waves). Each wave holds q-frags for all 4 j-subtiles (64 j) and
// covers a 256-row i-chunk (16 iters, 2 loads amortized over 12 MFMAs).
// Cross-wave top-2 merge in LDS, ascending-w = ascending-i (first-occurrence
// tie-break preserved; ties flagged -> exact recheck).
// ---------------------------------------------------------------------------
__global__ __launch_bounds__(1024) void energy_approx(
    const unsigned short* __restrict__ khi, const unsigned short* __restrict__ klo,
    const unsigned short* __restrict__ qhi, const unsigned short* __restrict__ qlo,
    float* __restrict__ star, int* __restrict__ argb,
    int* __restrict__ cnt, int* __restrict__ list) {
  int b = blockIdx.y;
  int j0 = blockIdx.x * 64;
  int tid = threadIdx.x;
  int lane = tid & 63, wv = tid >> 6;   // wv 0..15
  int lm = lane & 15, lq = lane >> 4;

  __shared__ float bv1S[16][64];
  __shared__ int   bi1S[16][64];
  __shared__ float bv2S[16][64];

  bf16x8 qh[4], ql[4];
#pragma unroll
  for (int s = 0; s < 4; ++s) {
    int j = j0 + s * 16 + lm;
    qh[s] = *reinterpret_cast<const bf16x8*>(qhi + ((size_t)b * HWn + j) * 32 + lq * 8);
    ql[s] = *reinterpret_cast<const bf16x8*>(qlo + ((size_t)b * HWn + j) * 32 + lq * 8);
  }
  const unsigned short* kh_base = khi + (size_t)b * HWn * 32 + lq * 8;
  const unsigned short* kl_base = klo + (size_t)b * HWn * 32 + lq * 8;

  float b1[4], b2[4];
  int i1[4];
#pragma unroll
  for (int s = 0; s < 4; ++s) { b1[s] = -3.0e38f; b2[s] = -3.0e38f; i1[s] = 0; }

  int ibase = wv * 256;
#pragma unroll 2
  for (int it = 0; it < 16; ++it) {
    int i0 = ibase + it * 16;
    bf16x8 ah = *reinterpret_cast<const bf16x8*>(kh_base + (size_t)(i0 + lm) * 32);
    bf16x8 al = *reinterpret_cast<const bf16x8*>(kl_base + (size_t)(i0 + lm) * 32);
#pragma unroll
    for (int s = 0; s < 4; ++s) {
      floatx4 acc = (floatx4)0.0f;   // 3 chained MFMAs; chains indep across s
      acc = __builtin_amdgcn_mfma_f32_16x16x32_bf16(ah, qh[s], acc, 0, 0, 0);
      acc = __builtin_amdgcn_mfma_f32_16x16x32_bf16(ah, ql[s], acc, 0, 0, 0);
      acc = __builtin_amdgcn_mfma_f32_16x16x32_bf16(al, qh[s], acc, 0, 0, 0);
      float m4 = fmaxf(fmaxf(acc[0], acc[1]), fmaxf(acc[2], acc[3]));
      if (m4 > b1[s]) {  // rare: exact top-2 maintenance
        int ib = i0 + lq * 4;
#pragma unroll
        for (int r = 0; r < 4; ++r) {
          float s2 = acc[r];
          if (s2 > b1[s]) { b2[s] = b1[s]; b1[s] = s2; i1[s] = ib + r; }
          else b2[s] = fmaxf(b2[s], s2);
        }
      } else {
        b2[s] = fmaxf(b2[s], m4);
      }
    }
  }
  // intra-wave: merge the 4 quads holding the same j
#pragma unroll
  for (int s = 0; s < 4; ++s) {
#pragma unroll
    for (int m = 16; m <= 32; m <<= 1) {
      float ob1 = __shfl_xor(b1[s], m, 64);
      int oi1 = __shfl_xor(i1[s], m, 64);
      float ob2 = __shfl_xor(b2[s], m, 64);
      float c2;
      if (ob1 > b1[s] || (ob1 == b1[s] && oi1 < i1[s])) {
        c2 = fmaxf(b1[s], ob2);
        b1[s] = ob1; i1[s] = oi1;
      } else {
        c2 = fmaxf(ob1, b2[s]);
      }
      b2[s] = c2;
    }
    if (lq == 0) {
      bv1S[wv][s * 16 + lm] = b1[s];
      bi1S[wv][s * 16 + lm] = i1[s];
      bv2S[wv][s * 16 + lm] = b2[s];
    }
  }
  __syncthreads();
  // cross-wave merge: ascending w = ascending i => strict > keeps earliest
  if (tid < 64) {
    float B1 = bv1S[0][tid];
    int I1 = bi1S[0][tid];
    float B2 = bv2S[0][tid];
#pragma unroll
    for (int w = 1; w < 16; ++w) {
      float v1 = bv1S[w][tid];
      int ii = bi1S[w][tid];
      float v2 = bv2S[w][tid];
      if (v1 > B1) { B2 = fmaxf(B1, v2); B1 = v1; I1 = ii; }
      else B2 = fmaxf(B2, v1);
    }
    size_t o = (size_t)b * HWn + j0 + tid;
    star[o] = B1;
    argb[o] = I1;
    if (B1 - B2 < MARGIN) {
      int slot = atomicAdd(cnt, 1);
      list[slot] = (b << 12) | (j0 + tid);
    }
  }
}

// ---------------------------------------------------------------------------
// K3: exact fp64 recheck over the compacted flagged list (unchanged).
// ---------------------------------------------------------------------------
__global__ __launch_bounds__(256) void recheck(
    const double* __restrict__ qd, const double* __restrict__ kd,
    const int* __restrict__ cnt, const int* __restrict__ list,
    float* __restrict__ star, int* __restrict__ argb) {
  __shared__ double bvS[4];
  __shared__ int biS[4];
  int n = cnt[0];
  int tid = threadIdx.x;
  int lane = tid & 63, wv = tid >> 6;
  for (int idx = blockIdx.x; idx < n; idx += gridDim.x) {
    int e = list[idx];
    int b = e >> 12, j = e & 4095;
    const double* qp = qd + ((size_t)b * HWn + j) * 32;
    double qj[32];
#pragma unroll
    for (int o = 0; o < 32; ++o) qj[o] = qp[o];
    double best = -1.0e300;
    int bi = 1 << 30;
    for (int i = tid; i < HWn; i += 256) {
      const double* kp = kd + ((size_t)b * HWn + i) * 32;
      double s = 0.0;
#pragma unroll
      for (int o = 0; o < 32; ++o) s += kp[o] * qj[o];
      if (s > best) { best = s; bi = i; }
    }
#pragma unroll
    for (int m = 1; m < 64; m <<= 1) {
      double ob = __shfl_xor(best, m, 64);
      int oi = __shfl_xor(bi, m, 64);
      if (ob > best || (ob == best && oi < bi)) { best = ob; bi = oi; }
    }
    if (lane == 0) { bvS[wv] = best; biS[wv] = bi; }
    __syncthreads();
    if (tid == 0) {
#pragma unroll
      for (int w = 1; w < 4; ++w) {
        if (bvS[w] > best || (bvS[w] == best && biS[w] < bi)) {
          best = bvS[w]; bi = biS[w];
        }
      }
      star[(size_t)b * HWn + j] = (float)best;
      argb[(size_t)b * HWn + j] = bi;
    }
    __syncthreads();
  }
}

// ---------------------------------------------------------------------------
// K4: transpose to bf16 pixel-major (unchanged).
// ---------------------------------------------------------------------------
__global__ __launch_bounds__(256) void cat_fx(
    const float* __restrict__ fx, const float* __restrict__ fxh,
    unsigned short* __restrict__ catC, unsigned short* __restrict__ xht) {
  int j0 = blockIdx.x * 64;
  int ci0 = blockIdx.y * 64;
  int b = blockIdx.z >> 1;
  int which = blockIdx.z & 1;
  int tid = threadIdx.x;
  __shared__ unsigned short tile[64][66];

  const float* src = (which == 0) ? fx : fxh;
  for (int u = tid; u < 4096; u += 256) {
    int cl = u >> 6, hw_l = u & 63;
    tile[cl][hw_l] = f2bf(src[((size_t)(b * Cn + ci0 + cl)) * HWn + j0 + hw_l]);
  }
  __syncthreads();
  if (which == 0) {
    for (int u = tid; u < 4096; u += 256) {
      int hw_l = u >> 6, cl = u & 63;
      catC[((size_t)b * ROWS + PADR + j0 + hw_l) * 512 + ci0 + cl] = tile[cl][hw_l];
    }
  } else {
    for (int u = tid; u < 4096; u += 256) {
      int hw_l = u >> 6, cl = u & 63;
      xht[((size_t)b * HWn + j0 + hw_l) * 256 + ci0 + cl] = tile[cl][hw_l];
    }
  }
}

// ---------------------------------------------------------------------------
// K5: v projection as bf16 MFMA GEMM (unchanged).
// ---------------------------------------------------------------------------
__global__ __launch_bounds__(256) void proj_v_mfma(
    const unsigned short* __restrict__ xht, const unsigned short* __restrict__ Wvb,
    const float* __restrict__ bv, unsigned short* __restrict__ vbf) {
  int m0 = blockIdx.x * 128;
  int o0 = blockIdx.y * 128;
  int b = blockIdx.z;
  int tid = threadIdx.x;
  int lane = tid & 63, wv = tid >> 6;
  int wm = wv >> 1, wn = wv & 1;
  int lm = lane & 15, lq = lane >> 4;

  __shared__ __align__(16) unsigned short AS[128 * 32];
  __shared__ __align__(16) unsigned short BS[128 * 32];
  __shared__ __align__(16) unsigned short TS[128 * 136];

  floatx4 acc[4][4];
#pragma unroll
  for (int im = 0; im < 4; ++im)
#pragma unroll
    for (int in = 0; in < 4; ++in) acc[im][in] = (floatx4)0.0f;

  const int srow = lane >> 2, soff = (lane & 3) * 8;
  const unsigned short* ag = Wvb + (size_t)o0 * 256;
  const unsigned short* bg = xht + ((size_t)b * HWn + m0) * 256;

  for (int kc = 0; kc < 256; kc += 32) {
    __syncthreads();
#pragma unroll
    for (int i = 0; i < 2; ++i) {
      int r0 = wv * 32 + i * 16;
      gl_lds16(ag + ((size_t)(r0 + srow)) * 256 + kc + soff, &AS[r0 * 32]);
      gl_lds16(bg + ((size_t)(r0 + srow)) * 256 + kc + soff, &BS[r0 * 32]);
    }
    __syncthreads();

    bf16x8 afr[4];
#pragma unroll
    for (int im = 0; im < 4; ++im)
      afr[im] = *reinterpret_cast<const bf16x8*>(
          &AS[(wm * 64 + im * 16 + lm) * 32 + lq * 8]);
#pragma unroll
    for (int in = 0; in < 4; ++in) {
      bf16x8 bfr = *reinterpret_cast<const bf16x8*>(
          &BS[(wn * 64 + in * 16 + lm) * 32 + lq * 8]);
#pragma unroll
      for (int im = 0; im < 4; ++im)
        acc[im][in] = __builtin_amdgcn_mfma_f32_16x16x32_bf16(
            afr[im], bfr, acc[im][in], 0, 0, 0);
    }
  }

  __syncthreads();
#pragma unroll
  for (int in = 0; in < 4; ++in) {
    int pl = wn * 64 + in * 16 + lm;
#pragma unroll
    for (int im = 0; im < 4; ++im) {
#pragma unroll
      for (int r = 0; r < 4; ++r) {
        int ol = wm * 64 + im * 16 + lq * 4 + r;
        TS[pl * 136 + ol] = f2bf(acc[im][in][r] + bv[o0 + ol]);
      }
    }
  }
  __syncthreads();
  for (int idx = tid; idx < 128 * 16; idx += 256) {
    int p = idx >> 4, ch = idx & 15;
    u16x8 val = *reinterpret_cast<const u16x8*>(&TS[p * 136 + ch * 8]);
    *reinterpret_cast<u16x8*>(
        &vbf[((size_t)b * HWn + m0 + p) * 256 + o0 + ch * 8]) = val;
  }
}

// ---------------------------------------------------------------------------
// K6: gather (unchanged).
// ---------------------------------------------------------------------------
__global__ __launch_bounds__(256) void gather_cat(
    const unsigned short* __restrict__ vbf, const int* __restrict__ argb,
    unsigned short* __restrict__ catC) {
  int b = blockIdx.y;
  int tid = threadIdx.x;
  if (blockIdx.x == 16) {
    for (int u = tid; u < 2 * PADR * 512; u += 256) {
      int r = u >> 9;
      int rr = (r < PADR) ? r : (HWn + r);
      catC[((size_t)b * ROWS + rr) * 512 + (u & 511)] = 0;
    }
    return;
  }
  __shared__ int ajS[256];
  int j0 = blockIdx.x * 256;
  ajS[tid] = argb[(size_t)b * HWn + j0 + tid];
  __syncthreads();
#pragma unroll 4
  for (int u = tid; u < 256 * 32; u += 256) {
    int pl = u >> 5, ch = u & 31;
    int aj = ajS[pl];
    u16x8 val = *reinterpret_cast<const u16x8*>(
        &vbf[((size_t)b * HWn + aj) * 256 + ch * 8]);
    *reinterpret_cast<u16x8*>(
        &catC[((size_t)b * ROWS + PADR + j0 + pl) * 512 + 256 + ch * 8]) = val;
  }
}

// ---------------------------------------------------------------------------
// K7: conv3x3 implicit GEMM on MFMA bf16 + epilogue (unchanged).
// ---------------------------------------------------------------------------
__global__ __launch_bounds__(256) void conv_mfma(
    const unsigned short* __restrict__ catC, const unsigned short* __restrict__ Wfb,
    const float* __restrict__ bf, const float* __restrict__ star,
    const float* __restrict__ fx, float* __restrict__ out) {
  int m0 = blockIdx.x * 128;
  int o0 = blockIdx.y * 128;
  int b = blockIdx.z;
  int tid = threadIdx.x;
  int lane = tid & 63;
  int wv = tid >> 6;
  int wm = wv >> 1;
  int wn = wv & 1;
  int lm = lane & 15, lq = lane >> 4;
  const bool lane_first = (lm == 0);
  const bool lane_last = (lm == 15);

  __shared__ __align__(16) unsigned short AS[128 * 32];
  __shared__ __align__(16) unsigned short BS[128 * 32];

  floatx4 acc[4][4];
#pragma unroll
  for (int im = 0; im < 4; ++im)
#pragma unroll
    for (int in = 0; in < 4; ++in) acc[im][in] = (floatx4)0.0f;

  const int srow = lane >> 2, soff = (lane & 3) * 8;

  for (int tap = 0; tap < 9; ++tap) {
    int dy = tap / 3 - 1, dx = tap % 3 - 1;
    const unsigned short* bg =
        catC + ((size_t)b * ROWS + PADR + m0 + dy * 64 + dx) * 512;
    const unsigned short* ag = Wfb + ((size_t)tap * 256 + o0) * 512;
    int killsel = dx;

    for (int kc = 0; kc < 512; kc += 32) {
      __syncthreads();
#pragma unroll
      for (int i = 0; i < 2; ++i) {
        int r0 = wv * 32 + i * 16;
        gl_lds16(ag + ((size_t)(r0 + srow)) * 512 + kc + soff, &AS[r0 * 32]);
        gl_lds16(bg + ((size_t)(r0 + srow)) * 512 + kc + soff, &BS[r0 * 32]);
      }
      __syncthreads();

      bf16x8 afr[4];
#pragma unroll
      for (int im = 0; im < 4; ++im)
        afr[im] = *reinterpret_cast<const bf16x8*>(
            &AS[(wm * 64 + im * 16 + lm) * 32 + lq * 8]);

#pragma unroll
      for (int in = 0; in < 4; ++in) {
        u16x8 braw = *reinterpret_cast<const u16x8*>(
            &BS[(wn * 64 + in * 16 + lm) * 32 + lq * 8]);
        if ((killsel == -1 && in == 0 && lane_first) ||
            (killsel == 1 && in == 3 && lane_last))
          braw = (u16x8)(unsigned short)0;
        union { u16x8 u; bf16x8 h; } cvt; cvt.u = braw;
#pragma unroll
        for (int im = 0; im < 4; ++im)
          acc[im][in] = __builtin_amdgcn_mfma_f32_16x16x32_bf16(
              afr[im], cvt.h, acc[im][in], 0, 0, 0);
      }
    }
  }

#pragma unroll
  for (int in = 0; in < 4; ++in) {
    int p = m0 + wn * 64 + in * 16 + lm;
    float Sp = star[(size_t)b * HWn + p];
#pragma unroll
    for (int im = 0; im < 4; ++im) {
      int ob = o0 + wm * 64 + im * 16 + lq * 4;
#pragma unroll
      for (int r = 0; r < 4; ++r) {
        int o = ob + r;
        size_t idx = ((size_t)(b * Cn + o)) * HWn + p;
        out[idx] = fx[idx] + (acc[im][in][r] + bf[o]) * Sp;
      }
    }
  }
}

// ---------------------------------------------------------------------------
extern "C" void kernel_launch(void* const* d_in, const int* in_sizes, int n_in,
                              void* d_out, int out_size, void* d_ws, size_t ws_size,
                              hipStream_t stream) {
  const float* front_x   = (const float*)d_in[0];
  const float* cross_x   = (const float*)d_in[1];
  const float* front_hat = (const float*)d_in[2];
  const float* Wq = (const float*)d_in[3];
  const float* bq = (const float*)d_in[4];
  const float* Wk = (const float*)d_in[5];
  const float* bk = (const float*)d_in[6];
  const float* Wv = (const float*)d_in[7];
  const float* bv = (const float*)d_in[8];
  const float* Wf = (const float*)d_in[9];
  const float* bf = (const float*)d_in[10];
  float* out = (float*)d_out;

  char* ws = (char*)d_ws;
  size_t off = 0;
  auto alloc = [&](size_t bytes) -> void* {
    void* p = (void*)(ws + off);
    off += (bytes + 255) & ~(size_t)255;
    return p;
  };
  double* Wqt = (double*)alloc(8192 * sizeof(double));
  double* Wkt = (double*)alloc(8192 * sizeof(double));
  double* bqd = (double*)alloc(32 * sizeof(double));
  double* bkd = (double*)alloc(32 * sizeof(double));
  unsigned short* Wvb = (unsigned short*)alloc(65536 * sizeof(unsigned short));
  unsigned short* Wfb = (unsigned short*)alloc((size_t)9 * 256 * 512 * sizeof(unsigned short));
  double* qd  = (double*)alloc((size_t)Bn * HWn * C8 * sizeof(double));
  double* kd  = (double*)alloc((size_t)Bn * HWn * C8 * sizeof(double));
  unsigned short* qhi = (unsigned short*)alloc((size_t)Bn * HWn * C8 * 2);
  unsigned short* qlo = (unsigned short*)alloc((size_t)Bn * HWn * C8 * 2);
  unsigned short* khi = (unsigned short*)alloc((size_t)Bn * HWn * C8 * 2);
  unsigned short* klo = (unsigned short*)alloc((size_t)Bn * HWn * C8 * 2);
  float*  star = (float*)alloc((size_t)Bn * HWn * sizeof(float));
  int*    argb = (int*)alloc((size_t)Bn * HWn * sizeof(int));
  int*    cnt  = (int*)alloc(256);
  int*    list = (int*)alloc((size_t)Bn * HWn * sizeof(int));
  unsigned short* xht = (unsigned short*)alloc((size_t)Bn * HWn * 256 * 2);
  unsigned short* vbf = (unsigned short*)alloc((size_t)Bn * HWn * 256 * 2);
  unsigned short* catC = (unsigned short*)alloc((size_t)Bn * ROWS * 512 * sizeof(unsigned short));

  prep_w<<<dim3((9 * 256 * 512 + 255) / 256), dim3(256), 0, stream>>>(
      Wq, bq, Wk, bk, Wv, Wf, Wqt, bqd, Wkt, bkd, Wvb, Wfb, cnt);

  proj_qk<<<dim3(HWn / 64, Bn, 2), dim3(256), 0, stream>>>(
      cross_x, front_x, Wqt, bqd, Wkt, bkd, qd, kd, qhi, qlo, khi, klo);

  energy_approx<<<dim3(HWn / 64, Bn), dim3(1024), 0, stream>>>(
      khi, klo, qhi, qlo, star, argb, cnt, list);

  recheck<<<dim3(256), dim3(256), 0, stream>>>(qd, kd, cnt, list, star, argb);

  cat_fx<<<dim3(HWn / 64, Cn / 64, Bn * 2), dim3(256), 0, stream>>>(
      front_x, front_hat, catC, xht);

  proj_v_mfma<<<dim3(HWn / 128, Cn / 128, Bn), dim3(256), 0, stream>>>(
      xht, Wvb, bv, vbf);

  gather_cat<<<dim3(HWn / 256 + 1, Bn), dim3(256), 0, stream>>>(vbf, argb, catC);

  conv_mfma<<<dim3(HWn / 128, Cn / 128, Bn), dim3(256), 0, stream>>>(
      catC, Wfb, bf, star, front_x, out);
}

// Round 7
// 372.633 us; speedup vs baseline: 1.9409x; 1.0920x over previous
//
#include <hip/hip_runtime.h>

#define Bn 4
#define Cn 256
#define C8 32
#define Hn 64
#define Wn 64
#define HWn 4096
#define PADR 66
#define ROWS (HWn + 2 * PADR)   // 4228 padded pixel-rows per batch
#define MARGIN 6e-3f

typedef __bf16 bf16x8 __attribute__((ext_vector_type(8)));
typedef float floatx4 __attribute__((ext_vector_type(4)));
typedef unsigned short u16x8 __attribute__((ext_vector_type(8)));

__device__ __forceinline__ unsigned short f2bf(float f) {
  union { float f; unsigned int u; } c; c.f = f;
  unsigned int u = c.u;
  return (unsigned short)((u + 0x7FFFu + ((u >> 16) & 1u)) >> 16);  // RNE
}
__device__ __forceinline__ float bf2f(unsigned short h) {
  union { unsigned int u; float f; } c; c.u = ((unsigned int)h) << 16;
  return c.f;
}
__device__ __forceinline__ void gl_lds16(const void* g, void* l) {
  __builtin_amdgcn_global_load_lds(
      (__attribute__((address_space(1))) void*)(uintptr_t)g,
      (__attribute__((address_space(3))) void*)(uintptr_t)l, 16, 0, 0);
}

// ---------------------------------------------------------------------------
// K0: weight prep + zero flagged-query counter (unchanged).
// ---------------------------------------------------------------------------
__global__ void prep_w(const float* __restrict__ Wq, const float* __restrict__ bq,
                       const float* __restrict__ Wk, const float* __restrict__ bk,
                       const float* __restrict__ Wv, const float* __restrict__ Wf,
                       double* __restrict__ Wqt, double* __restrict__ bqd,
                       double* __restrict__ Wkt, double* __restrict__ bkd,
                       unsigned short* __restrict__ Wvb, unsigned short* __restrict__ Wfb,
                       int* __restrict__ cnt) {
  size_t t = (size_t)blockIdx.x * 256 + threadIdx.x;
  if (t == 0) cnt[0] = 0;
  if (t < 8192) {
    int o = (int)(t / 256), c = (int)(t % 256);
    Wqt[(size_t)c * 32 + o] = (double)Wq[t];
    Wkt[(size_t)c * 32 + o] = (double)Wk[t];
  }
  if (t < 32) { bqd[t] = (double)bq[t]; bkd[t] = (double)bk[t]; }
  if (t < 65536) Wvb[t] = f2bf(Wv[t]);   // [o][c] row-major already
  if (t < (size_t)9 * 256 * 512) {
    int tap = (int)(t / (256 * 512));
    int rem = (int)(t % (256 * 512));
    int o = rem / 512, ci = rem % 512;
    Wfb[t] = f2bf(Wf[((size_t)o * 512 + ci) * 9 + tap]);
  }
}

// ---------------------------------------------------------------------------
// K1: q/k projection fp64, occupancy-fixed v2: 1024-thr blocks (16 waves).
// wave = (o-slice 0..3) x (c-chunk 0..3); each wave does 64 c-iterations
// (unroll 8 -> 8 loads in flight). c-chunk partials merged via 48KB LDS
// ([chunk][slice][o][lane], lane-innermost). 8192 waves = 32/CU.
// fp64 math identical to R6 (argmax semantics preserved).
// ---------------------------------------------------------------------------
__global__ __launch_bounds__(1024) void proj_qk(
    const float* __restrict__ cross_x, const float* __restrict__ front_x,
    const double* __restrict__ Wqt, const double* __restrict__ bqd,
    const double* __restrict__ Wkt, const double* __restrict__ bkd,
    double* __restrict__ qd, double* __restrict__ kd,
    unsigned short* __restrict__ qhi, unsigned short* __restrict__ qlo,
    unsigned short* __restrict__ khi, unsigned short* __restrict__ klo) {
  int tid = threadIdx.x;
  int lane = tid & 63, wv = tid >> 6;    // 16 waves
  int slice = wv & 3;                    // o-slice (8 o each)
  int chunk = wv >> 2;                   // c-chunk (64 c each)
  int j = blockIdx.x * 64 + lane;
  int b = blockIdx.y;
  int z = blockIdx.z;
  const float* x = (z == 0) ? cross_x : front_x;
  const double* Wt = (z == 0) ? Wqt : Wkt;
  const double* bd = (z == 0) ? bqd : bkd;
  double* outp = (z == 0) ? qd : kd;
  unsigned short* hip_ = (z == 0) ? qhi : khi;
  unsigned short* lop_ = (z == 0) ? qlo : klo;
  int o0 = slice * 8;
  int c0 = chunk * 64;

  __shared__ double part[3 * 4 * 8 * 64];  // [chunk-1][slice][o][lane] 48KB

  const float* xb = x + (size_t)b * Cn * HWn + j;
  double acc[8];
#pragma unroll
  for (int o = 0; o < 8; ++o) acc[o] = (chunk == 0) ? bd[o0 + o] : 0.0;
#pragma unroll 8
  for (int c = c0; c < c0 + 64; ++c) {
    double xv = (double)xb[(size_t)c * HWn];
    const double* wrow = Wt + (size_t)c * C8 + o0;  // wave-uniform 64B
#pragma unroll
    for (int o = 0; o < 8; ++o) acc[o] += wrow[o] * xv;
  }
  if (chunk > 0) {
    double* dst = &part[(((chunk - 1) * 4 + slice) * 8) * 64];
#pragma unroll
    for (int o = 0; o < 8; ++o) dst[o * 64 + lane] = acc[o];
  }
  __syncthreads();
  if (chunk != 0) return;
#pragma unroll
  for (int q = 0; q < 3; ++q) {
    const double* src = &part[((q * 4 + slice) * 8) * 64];
#pragma unroll
    for (int o = 0; o < 8; ++o) acc[o] += src[o * 64 + lane];
  }
  double* op = outp + ((size_t)b * HWn + j) * C8 + o0;
  u16x8 hv, lv;
#pragma unroll
  for (int o = 0; o < 8; ++o) {
    op[o] = acc[o];
    float f = (float)acc[o];
    unsigned short h = f2bf(f);
    hv[o] = h;
    lv[o] = f2bf(f - bf2f(h));
  }
  *reinterpret_cast<u16x8*>(hip_ + ((size_t)b * HWn + j) * C8 + o0) = hv;
  *reinterpret_cast<u16x8*>(lop_ + ((size_t)b * HWn + j) * C8 + o0) = lv;
}

// ---------------------------------------------------------------------------
// K2: approximate energy via split-bf16 MFMA (unchanged from R6).
// ---------------------------------------------------------------------------
__global__ __launch_bounds__(1024) void energy_approx(
    const unsigned short* __restrict__ khi, const unsigned short* __restrict__ klo,
    const unsigned short* __restrict__ qhi, const unsigned short* __restrict__ qlo,
    float* __restrict__ star, int* __restrict__ argb,
    int* __restrict__ cnt, int* __restrict__ list) {
  int b = blockIdx.y;
  int j0 = blockIdx.x * 64;
  int tid = threadIdx.x;
  int lane = tid & 63, wv = tid >> 6;   // wv 0..15
  int lm = lane & 15, lq = lane >> 4;

  __shared__ float bv1S[16][64];
  __shared__ int   bi1S[16][64];
  __shared__ float bv2S[16][64];

  bf16x8 qh[4], ql[4];
#pragma unroll
  for (int s = 0; s < 4; ++s) {
    int j = j0 + s * 16 + lm;
    qh[s] = *reinterpret_cast<const bf16x8*>(qhi + ((size_t)b * HWn + j) * 32 + lq * 8);
    ql[s] = *reinterpret_cast<const bf16x8*>(qlo + ((size_t)b * HWn + j) * 32 + lq * 8);
  }
  const unsigned short* kh_base = khi + (size_t)b * HWn * 32 + lq * 8;
  const unsigned short* kl_base = klo + (size_t)b * HWn * 32 + lq * 8;

  float b1[4], b2[4];
  int i1[4];
#pragma unroll
  for (int s = 0; s < 4; ++s) { b1[s] = -3.0e38f; b2[s] = -3.0e38f; i1[s] = 0; }

  int ibase = wv * 256;
#pragma unroll 2
  for (int it = 0; it < 16; ++it) {
    int i0 = ibase + it * 16;
    bf16x8 ah = *reinterpret_cast<const bf16x8*>(kh_base + (size_t)(i0 + lm) * 32);
    bf16x8 al = *reinterpret_cast<const bf16x8*>(kl_base + (size_t)(i0 + lm) * 32);
#pragma unroll
    for (int s = 0; s < 4; ++s) {
      floatx4 acc = (floatx4)0.0f;
      acc = __builtin_amdgcn_mfma_f32_16x16x32_bf16(ah, qh[s], acc, 0, 0, 0);
      acc = __builtin_amdgcn_mfma_f32_16x16x32_bf16(ah, ql[s], acc, 0, 0, 0);
      acc = __builtin_amdgcn_mfma_f32_16x16x32_bf16(al, qh[s], acc, 0, 0, 0);
      float m4 = fmaxf(fmaxf(acc[0], acc[1]), fmaxf(acc[2], acc[3]));
      if (m4 > b1[s]) {
        int ib = i0 + lq * 4;
#pragma unroll
        for (int r = 0; r < 4; ++r) {
          float s2 = acc[r];
          if (s2 > b1[s]) { b2[s] = b1[s]; b1[s] = s2; i1[s] = ib + r; }
          else b2[s] = fmaxf(b2[s], s2);
        }
      } else {
        b2[s] = fmaxf(b2[s], m4);
      }
    }
  }
#pragma unroll
  for (int s = 0; s < 4; ++s) {
#pragma unroll
    for (int m = 16; m <= 32; m <<= 1) {
      float ob1 = __shfl_xor(b1[s], m, 64);
      int oi1 = __shfl_xor(i1[s], m, 64);
      float ob2 = __shfl_xor(b2[s], m, 64);
      float c2;
      if (ob1 > b1[s] || (ob1 == b1[s] && oi1 < i1[s])) {
        c2 = fmaxf(b1[s], ob2);
        b1[s] = ob1; i1[s] = oi1;
      } else {
        c2 = fmaxf(ob1, b2[s]);
      }
      b2[s] = c2;
    }
    if (lq == 0) {
      bv1S[wv][s * 16 + lm] = b1[s];
      bi1S[wv][s * 16 + lm] = i1[s];
      bv2S[wv][s * 16 + lm] = b2[s];
    }
  }
  __syncthreads();
  if (tid < 64) {
    float B1 = bv1S[0][tid];
    int I1 = bi1S[0][tid];
    float B2 = bv2S[0][tid];
#pragma unroll
    for (int w = 1; w < 16; ++w) {
      float v1 = bv1S[w][tid];
      int ii = bi1S[w][tid];
      float v2 = bv2S[w][tid];
      if (v1 > B1) { B2 = fmaxf(B1, v2); B1 = v1; I1 = ii; }
      else B2 = fmaxf(B2, v1);
    }
    size_t o = (size_t)b * HWn + j0 + tid;
    star[o] = B1;
    argb[o] = I1;
    if (B1 - B2 < MARGIN) {
      int slot = atomicAdd(cnt, 1);
      list[slot] = (b << 12) | (j0 + tid);
    }
  }
}

// ---------------------------------------------------------------------------
// K3: exact fp64 recheck over the compacted flagged list (unchanged).
// ---------------------------------------------------------------------------
__global__ __launch_bounds__(256) void recheck(
    const double* __restrict__ qd, const double* __restrict__ kd,
    const int* __restrict__ cnt, const int* __restrict__ list,
    float* __restrict__ star, int* __restrict__ argb) {
  __shared__ double bvS[4];
  __shared__ int biS[4];
  int n = cnt[0];
  int tid = threadIdx.x;
  int lane = tid & 63, wv = tid >> 6;
  for (int idx = blockIdx.x; idx < n; idx += gridDim.x) {
    int e = list[idx];
    int b = e >> 12, j = e & 4095;
    const double* qp = qd + ((size_t)b * HWn + j) * 32;
    double qj[32];
#pragma unroll
    for (int o = 0; o < 32; ++o) qj[o] = qp[o];
    double best = -1.0e300;
    int bi = 1 << 30;
    for (int i = tid; i < HWn; i += 256) {
      const double* kp = kd + ((size_t)b * HWn + i) * 32;
      double s = 0.0;
#pragma unroll
      for (int o = 0; o < 32; ++o) s += kp[o] * qj[o];
      if (s > best) { best = s; bi = i; }
    }
#pragma unroll
    for (int m = 1; m < 64; m <<= 1) {
      double ob = __shfl_xor(best, m, 64);
      int oi = __shfl_xor(bi, m, 64);
      if (ob > best || (ob == best && oi < bi)) { best = ob; bi = oi; }
    }
    if (lane == 0) { bvS[wv] = best; biS[wv] = bi; }
    __syncthreads();
    if (tid == 0) {
#pragma unroll
      for (int w = 1; w < 4; ++w) {
        if (bvS[w] > best || (bvS[w] == best && biS[w] < bi)) {
          best = bvS[w]; bi = biS[w];
        }
      }
      star[(size_t)b * HWn + j] = (float)best;
      argb[(size_t)b * HWn + j] = bi;
    }
    __syncthreads();
  }
}

// ---------------------------------------------------------------------------
// K4: transpose to bf16 pixel-major (unchanged).
// ---------------------------------------------------------------------------
__global__ __launch_bounds__(256) void cat_fx(
    const float* __restrict__ fx, const float* __restrict__ fxh,
    unsigned short* __restrict__ catC, unsigned short* __restrict__ xht) {
  int j0 = blockIdx.x * 64;
  int ci0 = blockIdx.y * 64;
  int b = blockIdx.z >> 1;
  int which = blockIdx.z & 1;
  int tid = threadIdx.x;
  __shared__ unsigned short tile[64][66];

  const float* src = (which == 0) ? fx : fxh;
  for (int u = tid; u < 4096; u += 256) {
    int cl = u >> 6, hw_l = u & 63;
    tile[cl][hw_l] = f2bf(src[((size_t)(b * Cn + ci0 + cl)) * HWn + j0 + hw_l]);
  }
  __syncthreads();
  if (which == 0) {
    for (int u = tid; u < 4096; u += 256) {
      int hw_l = u >> 6, cl = u & 63;
      catC[((size_t)b * ROWS + PADR + j0 + hw_l) * 512 + ci0 + cl] = tile[cl][hw_l];
    }
  } else {
    for (int u = tid; u < 4096; u += 256) {
      int hw_l = u >> 6, cl = u & 63;
      xht[((size_t)b * HWn + j0 + hw_l) * 256 + ci0 + cl] = tile[cl][hw_l];
    }
  }
}

// ---------------------------------------------------------------------------
// K5: v projection as bf16 MFMA GEMM (unchanged).
// ---------------------------------------------------------------------------
__global__ __launch_bounds__(256) void proj_v_mfma(
    const unsigned short* __restrict__ xht, const unsigned short* __restrict__ Wvb,
    const float* __restrict__ bv, unsigned short* __restrict__ vbf) {
  int m0 = blockIdx.x * 128;
  int o0 = blockIdx.y * 128;
  int b = blockIdx.z;
  int tid = threadIdx.x;
  int lane = tid & 63, wv = tid >> 6;
  int wm = wv >> 1, wn = wv & 1;
  int lm = lane & 15, lq = lane >> 4;

  __shared__ __align__(16) unsigned short AS[128 * 32];
  __shared__ __align__(16) unsigned short BS[128 * 32];
  __shared__ __align__(16) unsigned short TS[128 * 136];

  floatx4 acc[4][4];
#pragma unroll
  for (int im = 0; im < 4; ++im)
#pragma unroll
    for (int in = 0; in < 4; ++in) acc[im][in] = (floatx4)0.0f;

  const int srow = lane >> 2, soff = (lane & 3) * 8;
  const unsigned short* ag = Wvb + (size_t)o0 * 256;
  const unsigned short* bg = xht + ((size_t)b * HWn + m0) * 256;

  for (int kc = 0; kc < 256; kc += 32) {
    __syncthreads();
#pragma unroll
    for (int i = 0; i < 2; ++i) {
      int r0 = wv * 32 + i * 16;
      gl_lds16(ag + ((size_t)(r0 + srow)) * 256 + kc + soff, &AS[r0 * 32]);
      gl_lds16(bg + ((size_t)(r0 + srow)) * 256 + kc + soff, &BS[r0 * 32]);
    }
    __syncthreads();

    bf16x8 afr[4];
#pragma unroll
    for (int im = 0; im < 4; ++im)
      afr[im] = *reinterpret_cast<const bf16x8*>(
          &AS[(wm * 64 + im * 16 + lm) * 32 + lq * 8]);
#pragma unroll
    for (int in = 0; in < 4; ++in) {
      bf16x8 bfr = *reinterpret_cast<const bf16x8*>(
          &BS[(wn * 64 + in * 16 + lm) * 32 + lq * 8]);
#pragma unroll
      for (int im = 0; im < 4; ++im)
        acc[im][in] = __builtin_amdgcn_mfma_f32_16x16x32_bf16(
            afr[im], bfr, acc[im][in], 0, 0, 0);
    }
  }

  __syncthreads();
#pragma unroll
  for (int in = 0; in < 4; ++in) {
    int pl = wn * 64 + in * 16 + lm;
#pragma unroll
    for (int im = 0; im < 4; ++im) {
#pragma unroll
      for (int r = 0; r < 4; ++r) {
        int ol = wm * 64 + im * 16 + lq * 4 + r;
        TS[pl * 136 + ol] = f2bf(acc[im][in][r] + bv[o0 + ol]);
      }
    }
  }
  __syncthreads();
  for (int idx = tid; idx < 128 * 16; idx += 256) {
    int p = idx >> 4, ch = idx & 15;
    u16x8 val = *reinterpret_cast<const u16x8*>(&TS[p * 136 + ch * 8]);
    *reinterpret_cast<u16x8*>(
        &vbf[((size_t)b * HWn + m0 + p) * 256 + o0 + ch * 8]) = val;
  }
}

// ---------------------------------------------------------------------------
// K6: gather (unchanged).
// ---------------------------------------------------------------------------
__global__ __launch_bounds__(256) void gather_cat(
    const unsigned short* __restrict__ vbf, const int* __restrict__ argb,
    unsigned short* __restrict__ catC) {
  int b = blockIdx.y;
  int tid = threadIdx.x;
  if (blockIdx.x == 16) {
    for (int u = tid; u < 2 * PADR * 512; u += 256) {
      int r = u >> 9;
      int rr = (r < PADR) ? r : (HWn + r);
      catC[((size_t)b * ROWS + rr) * 512 + (u & 511)] = 0;
    }
    return;
  }
  __shared__ int ajS[256];
  int j0 = blockIdx.x * 256;
  ajS[tid] = argb[(size_t)b * HWn + j0 + tid];
  __syncthreads();
#pragma unroll 4
  for (int u = tid; u < 256 * 32; u += 256) {
    int pl = u >> 5, ch = u & 31;
    int aj = ajS[pl];
    u16x8 val = *reinterpret_cast<const u16x8*>(
        &vbf[((size_t)b * HWn + aj) * 256 + ch * 8]);
    *reinterpret_cast<u16x8*>(
        &catC[((size_t)b * ROWS + PADR + j0 + pl) * 512 + 256 + ch * 8]) = val;
  }
}

// ---------------------------------------------------------------------------
// K7: conv3x3 implicit GEMM on MFMA bf16 + epilogue (unchanged).
// ---------------------------------------------------------------------------
__global__ __launch_bounds__(256) void conv_mfma(
    const unsigned short* __restrict__ catC, const unsigned short* __restrict__ Wfb,
    const float* __restrict__ bf, const float* __restrict__ star,
    const float* __restrict__ fx, float* __restrict__ out) {
  int m0 = blockIdx.x * 128;
  int o0 = blockIdx.y * 128;
  int b = blockIdx.z;
  int tid = threadIdx.x;
  int lane = tid & 63;
  int wv = tid >> 6;
  int wm = wv >> 1;
  int wn = wv & 1;
  int lm = lane & 15, lq = lane >> 4;
  const bool lane_first = (lm == 0);
  const bool lane_last = (lm == 15);

  __shared__ __align__(16) unsigned short AS[128 * 32];
  __shared__ __align__(16) unsigned short BS[128 * 32];

  floatx4 acc[4][4];
#pragma unroll
  for (int im = 0; im < 4; ++im)
#pragma unroll
    for (int in = 0; in < 4; ++in) acc[im][in] = (floatx4)0.0f;

  const int srow = lane >> 2, soff = (lane & 3) * 8;

  for (int tap = 0; tap < 9; ++tap) {
    int dy = tap / 3 - 1, dx = tap % 3 - 1;
    const unsigned short* bg =
        catC + ((size_t)b * ROWS + PADR + m0 + dy * 64 + dx) * 512;
    const unsigned short* ag = Wfb + ((size_t)tap * 256 + o0) * 512;
    int killsel = dx;

    for (int kc = 0; kc < 512; kc += 32) {
      __syncthreads();
#pragma unroll
      for (int i = 0; i < 2; ++i) {
        int r0 = wv * 32 + i * 16;
        gl_lds16(ag + ((size_t)(r0 + srow)) * 512 + kc + soff, &AS[r0 * 32]);
        gl_lds16(bg + ((size_t)(r0 + srow)) * 512 + kc + soff, &BS[r0 * 32]);
      }
      __syncthreads();

      bf16x8 afr[4];
#pragma unroll
      for (int im = 0; im < 4; ++im)
        afr[im] = *reinterpret_cast<const bf16x8*>(
            &AS[(wm * 64 + im * 16 + lm) * 32 + lq * 8]);

#pragma unroll
      for (int in = 0; in < 4; ++in) {
        u16x8 braw = *reinterpret_cast<const u16x8*>(
            &BS[(wn * 64 + in * 16 + lm) * 32 + lq * 8]);
        if ((killsel == -1 && in == 0 && lane_first) ||
            (killsel == 1 && in == 3 && lane_last))
          braw = (u16x8)(unsigned short)0;
        union { u16x8 u; bf16x8 h; } cvt; cvt.u = braw;
#pragma unroll
        for (int im = 0; im < 4; ++im)
          acc[im][in] = __builtin_amdgcn_mfma_f32_16x16x32_bf16(
              afr[im], cvt.h, acc[im][in], 0, 0, 0);
      }
    }
  }

#pragma unroll
  for (int in = 0; in < 4; ++in) {
    int p = m0 + wn * 64 + in * 16 + lm;
    float Sp = star[(size_t)b * HWn + p];
#pragma unroll
    for (int im = 0; im < 4; ++im) {
      int ob = o0 + wm * 64 + im * 16 + lq * 4;
#pragma unroll
      for (int r = 0; r < 4; ++r) {
        int o = ob + r;
        size_t idx = ((size_t)(b * Cn + o)) * HWn + p;
        out[idx] = fx[idx] + (acc[im][in][r] + bf[o]) * Sp;
      }
    }
  }
}

// ---------------------------------------------------------------------------
extern "C" void kernel_launch(void* const* d_in, const int* in_sizes, int n_in,
                              void* d_out, int out_size, void* d_ws, size_t ws_size,
                              hipStream_t stream) {
  const float* front_x   = (const float*)d_in[0];
  const float* cross_x   = (const float*)d_in[1];
  const float* front_hat = (const float*)d_in[2];
  const float* Wq = (const float*)d_in[3];
  const float* bq = (const float*)d_in[4];
  const float* Wk = (const float*)d_in[5];
  const float* bk = (const float*)d_in[6];
  const float* Wv = (const float*)d_in[7];
  const float* bv = (const float*)d_in[8];
  const float* Wf = (const float*)d_in[9];
  const float* bf = (const float*)d_in[10];
  float* out = (float*)d_out;

  char* ws = (char*)d_ws;
  size_t off = 0;
  auto alloc = [&](size_t bytes) -> void* {
    void* p = (void*)(ws + off);
    off += (bytes + 255) & ~(size_t)255;
    return p;
  };
  double* Wqt = (double*)alloc(8192 * sizeof(double));
  double* Wkt = (double*)alloc(8192 * sizeof(double));
  double* bqd = (double*)alloc(32 * sizeof(double));
  double* bkd = (double*)alloc(32 * sizeof(double));
  unsigned short* Wvb = (unsigned short*)alloc(65536 * sizeof(unsigned short));
  unsigned short* Wfb = (unsigned short*)alloc((size_t)9 * 256 * 512 * sizeof(unsigned short));
  double* qd  = (double*)alloc((size_t)Bn * HWn * C8 * sizeof(double));
  double* kd  = (double*)alloc((size_t)Bn * HWn * C8 * sizeof(double));
  unsigned short* qhi = (unsigned short*)alloc((size_t)Bn * HWn * C8 * 2);
  unsigned short* qlo = (unsigned short*)alloc((size_t)Bn * HWn * C8 * 2);
  unsigned short* khi = (unsigned short*)alloc((size_t)Bn * HWn * C8 * 2);
  unsigned short* klo = (unsigned short*)alloc((size_t)Bn * HWn * C8 * 2);
  float*  star = (float*)alloc((size_t)Bn * HWn * sizeof(float));
  int*    argb = (int*)alloc((size_t)Bn * HWn * sizeof(int));
  int*    cnt  = (int*)alloc(256);
  int*    list = (int*)alloc((size_t)Bn * HWn * sizeof(int));
  unsigned short* xht = (unsigned short*)alloc((size_t)Bn * HWn * 256 * 2);
  unsigned short* vbf = (unsigned short*)alloc((size_t)Bn * HWn * 256 * 2);
  unsigned short* catC = (unsigned short*)alloc((size_t)Bn * ROWS * 512 * sizeof(unsigned short));

  prep_w<<<dim3((9 * 256 * 512 + 255) / 256), dim3(256), 0, stream>>>(
      Wq, bq, Wk, bk, Wv, Wf, Wqt, bqd, Wkt, bkd, Wvb, Wfb, cnt);

  proj_qk<<<dim3(HWn / 64, Bn, 2), dim3(1024), 0, stream>>>(
      cross_x, front_x, Wqt, bqd, Wkt, bkd, qd, kd, qhi, qlo, khi, klo);

  energy_approx<<<dim3(HWn / 64, Bn), dim3(1024), 0, stream>>>(
      khi, klo, qhi, qlo, star, argb, cnt, list);

  recheck<<<dim3(256), dim3(256), 0, stream>>>(qd, kd, cnt, list, star, argb);

  cat_fx<<<dim3(HWn / 64, Cn / 64, Bn * 2), dim3(256), 0, stream>>>(
      front_x, front_hat, catC, xht);

  proj_v_mfma<<<dim3(HWn / 128, Cn / 128, Bn), dim3(256), 0, stream>>>(
      xht, Wvb, bv, vbf);

  gather_cat<<<dim3(HWn / 256 + 1, Bn), dim3(256), 0, stream>>>(vbf, argb, catC);

  conv_mfma<<<dim3(HWn / 128, Cn / 128, Bn), dim3(256), 0, stream>>>(
      catC, Wfb, bf, star, front_x, out);
}

// Round 8
// 340.759 us; speedup vs baseline: 2.1225x; 1.0935x over previous
//
#include <hip/hip_runtime.h>

#define Bn 4
#define Cn 256
#define C8 32
#define Hn 64
#define Wn 64
#define HWn 4096
#define PADR 80
#define ROWS (HWn + 2 * PADR)   // 4256 padded pixel-rows per batch
#define MARGIN 6e-3f

typedef __bf16 bf16x8 __attribute__((ext_vector_type(8)));
typedef float floatx4 __attribute__((ext_vector_type(4)));
typedef unsigned short u16x8 __attribute__((ext_vector_type(8)));

__device__ __forceinline__ unsigned short f2bf(float f) {
  union { float f; unsigned int u; } c; c.f = f;
  unsigned int u = c.u;
  return (unsigned short)((u + 0x7FFFu + ((u >> 16) & 1u)) >> 16);  // RNE
}
__device__ __forceinline__ float bf2f(unsigned short h) {
  union { unsigned int u; float f; } c; c.u = ((unsigned int)h) << 16;
  return c.f;
}
__device__ __forceinline__ void gl_lds16(const void* g, void* l) {
  __builtin_amdgcn_global_load_lds(
      (__attribute__((address_space(1))) void*)(uintptr_t)g,
      (__attribute__((address_space(3))) void*)(uintptr_t)l, 16, 0, 0);
}

// ---------------------------------------------------------------------------
// K0: weight prep + zero flagged-query counter (unchanged).
// ---------------------------------------------------------------------------
__global__ void prep_w(const float* __restrict__ Wq, const float* __restrict__ bq,
                       const float* __restrict__ Wk, const float* __restrict__ bk,
                       const float* __restrict__ Wv, const float* __restrict__ Wf,
                       double* __restrict__ Wqt, double* __restrict__ bqd,
                       double* __restrict__ Wkt, double* __restrict__ bkd,
                       unsigned short* __restrict__ Wvb, unsigned short* __restrict__ Wfb,
                       int* __restrict__ cnt) {
  size_t t = (size_t)blockIdx.x * 256 + threadIdx.x;
  if (t == 0) cnt[0] = 0;
  if (t < 8192) {
    int o = (int)(t / 256), c = (int)(t % 256);
    Wqt[(size_t)c * 32 + o] = (double)Wq[t];
    Wkt[(size_t)c * 32 + o] = (double)Wk[t];
  }
  if (t < 32) { bqd[t] = (double)bq[t]; bkd[t] = (double)bk[t]; }
  if (t < 65536) Wvb[t] = f2bf(Wv[t]);   // [o][c] row-major already
  if (t < (size_t)9 * 256 * 512) {
    int tap = (int)(t / (256 * 512));
    int rem = (int)(t % (256 * 512));
    int o = rem / 512, ci = rem % 512;
    Wfb[t] = f2bf(Wf[((size_t)o * 512 + ci) * 9 + tap]);
  }
}

// ---------------------------------------------------------------------------
// K1: q/k projection fp64 (unchanged from R7).
// ---------------------------------------------------------------------------
__global__ __launch_bounds__(1024) void proj_qk(
    const float* __restrict__ cross_x, const float* __restrict__ front_x,
    const double* __restrict__ Wqt, const double* __restrict__ bqd,
    const double* __restrict__ Wkt, const double* __restrict__ bkd,
    double* __restrict__ qd, double* __restrict__ kd,
    unsigned short* __restrict__ qhi, unsigned short* __restrict__ qlo,
    unsigned short* __restrict__ khi, unsigned short* __restrict__ klo) {
  int tid = threadIdx.x;
  int lane = tid & 63, wv = tid >> 6;    // 16 waves
  int slice = wv & 3;                    // o-slice (8 o each)
  int chunk = wv >> 2;                   // c-chunk (64 c each)
  int j = blockIdx.x * 64 + lane;
  int b = blockIdx.y;
  int z = blockIdx.z;
  const float* x = (z == 0) ? cross_x : front_x;
  const double* Wt = (z == 0) ? Wqt : Wkt;
  const double* bd = (z == 0) ? bqd : bkd;
  double* outp = (z == 0) ? qd : kd;
  unsigned short* hip_ = (z == 0) ? qhi : khi;
  unsigned short* lop_ = (z == 0) ? qlo : klo;
  int o0 = slice * 8;
  int c0 = chunk * 64;

  __shared__ double part[3 * 4 * 8 * 64];  // [chunk-1][slice][o][lane] 48KB

  const float* xb = x + (size_t)b * Cn * HWn + j;
  double acc[8];
#pragma unroll
  for (int o = 0; o < 8; ++o) acc[o] = (chunk == 0) ? bd[o0 + o] : 0.0;
#pragma unroll 8
  for (int c = c0; c < c0 + 64; ++c) {
    double xv = (double)xb[(size_t)c * HWn];
    const double* wrow = Wt + (size_t)c * C8 + o0;  // wave-uniform 64B
#pragma unroll
    for (int o = 0; o < 8; ++o) acc[o] += wrow[o] * xv;
  }
  if (chunk > 0) {
    double* dst = &part[(((chunk - 1) * 4 + slice) * 8) * 64];
#pragma unroll
    for (int o = 0; o < 8; ++o) dst[o * 64 + lane] = acc[o];
  }
  __syncthreads();
  if (chunk != 0) return;
#pragma unroll
  for (int q = 0; q < 3; ++q) {
    const double* src = &part[((q * 4 + slice) * 8) * 64];
#pragma unroll
    for (int o = 0; o < 8; ++o) acc[o] += src[o * 64 + lane];
  }
  double* op = outp + ((size_t)b * HWn + j) * C8 + o0;
  u16x8 hv, lv;
#pragma unroll
  for (int o = 0; o < 8; ++o) {
    op[o] = acc[o];
    float f = (float)acc[o];
    unsigned short h = f2bf(f);
    hv[o] = h;
    lv[o] = f2bf(f - bf2f(h));
  }
  *reinterpret_cast<u16x8*>(hip_ + ((size_t)b * HWn + j) * C8 + o0) = hv;
  *reinterpret_cast<u16x8*>(lop_ + ((size_t)b * HWn + j) * C8 + o0) = lv;
}

// ---------------------------------------------------------------------------
// K2: approximate energy via split-bf16 MFMA (unchanged from R6).
// ---------------------------------------------------------------------------
__global__ __launch_bounds__(1024) void energy_approx(
    const unsigned short* __restrict__ khi, const unsigned short* __restrict__ klo,
    const unsigned short* __restrict__ qhi, const unsigned short* __restrict__ qlo,
    float* __restrict__ star, int* __restrict__ argb,
    int* __restrict__ cnt, int* __restrict__ list) {
  int b = blockIdx.y;
  int j0 = blockIdx.x * 64;
  int tid = threadIdx.x;
  int lane = tid & 63, wv = tid >> 6;   // wv 0..15
  int lm = lane & 15, lq = lane >> 4;

  __shared__ float bv1S[16][64];
  __shared__ int   bi1S[16][64];
  __shared__ float bv2S[16][64];

  bf16x8 qh[4], ql[4];
#pragma unroll
  for (int s = 0; s < 4; ++s) {
    int j = j0 + s * 16 + lm;
    qh[s] = *reinterpret_cast<const bf16x8*>(qhi + ((size_t)b * HWn + j) * 32 + lq * 8);
    ql[s] = *reinterpret_cast<const bf16x8*>(qlo + ((size_t)b * HWn + j) * 32 + lq * 8);
  }
  const unsigned short* kh_base = khi + (size_t)b * HWn * 32 + lq * 8;
  const unsigned short* kl_base = klo + (size_t)b * HWn * 32 + lq * 8;

  float b1[4], b2[4];
  int i1[4];
#pragma unroll
  for (int s = 0; s < 4; ++s) { b1[s] = -3.0e38f; b2[s] = -3.0e38f; i1[s] = 0; }

  int ibase = wv * 256;
#pragma unroll 2
  for (int it = 0; it < 16; ++it) {
    int i0 = ibase + it * 16;
    bf16x8 ah = *reinterpret_cast<const bf16x8*>(kh_base + (size_t)(i0 + lm) * 32);
    bf16x8 al = *reinterpret_cast<const bf16x8*>(kl_base + (size_t)(i0 + lm) * 32);
#pragma unroll
    for (int s = 0; s < 4; ++s) {
      floatx4 acc = (floatx4)0.0f;
      acc = __builtin_amdgcn_mfma_f32_16x16x32_bf16(ah, qh[s], acc, 0, 0, 0);
      acc = __builtin_amdgcn_mfma_f32_16x16x32_bf16(ah, ql[s], acc, 0, 0, 0);
      acc = __builtin_amdgcn_mfma_f32_16x16x32_bf16(al, qh[s], acc, 0, 0, 0);
      float m4 = fmaxf(fmaxf(acc[0], acc[1]), fmaxf(acc[2], acc[3]));
      if (m4 > b1[s]) {
        int ib = i0 + lq * 4;
#pragma unroll
        for (int r = 0; r < 4; ++r) {
          float s2 = acc[r];
          if (s2 > b1[s]) { b2[s] = b1[s]; b1[s] = s2; i1[s] = ib + r; }
          else b2[s] = fmaxf(b2[s], s2);
        }
      } else {
        b2[s] = fmaxf(b2[s], m4);
      }
    }
  }
#pragma unroll
  for (int s = 0; s < 4; ++s) {
#pragma unroll
    for (int m = 16; m <= 32; m <<= 1) {
      float ob1 = __shfl_xor(b1[s], m, 64);
      int oi1 = __shfl_xor(i1[s], m, 64);
      float ob2 = __shfl_xor(b2[s], m, 64);
      float c2;
      if (ob1 > b1[s] || (ob1 == b1[s] && oi1 < i1[s])) {
        c2 = fmaxf(b1[s], ob2);
        b1[s] = ob1; i1[s] = oi1;
      } else {
        c2 = fmaxf(ob1, b2[s]);
      }
      b2[s] = c2;
    }
    if (lq == 0) {
      bv1S[wv][s * 16 + lm] = b1[s];
      bi1S[wv][s * 16 + lm] = i1[s];
      bv2S[wv][s * 16 + lm] = b2[s];
    }
  }
  __syncthreads();
  if (tid < 64) {
    float B1 = bv1S[0][tid];
    int I1 = bi1S[0][tid];
    float B2 = bv2S[0][tid];
#pragma unroll
    for (int w = 1; w < 16; ++w) {
      float v1 = bv1S[w][tid];
      int ii = bi1S[w][tid];
      float v2 = bv2S[w][tid];
      if (v1 > B1) { B2 = fmaxf(B1, v2); B1 = v1; I1 = ii; }
      else B2 = fmaxf(B2, v1);
    }
    size_t o = (size_t)b * HWn + j0 + tid;
    star[o] = B1;
    argb[o] = I1;
    if (B1 - B2 < MARGIN) {
      int slot = atomicAdd(cnt, 1);
      list[slot] = (b << 12) | (j0 + tid);
    }
  }
}

// ---------------------------------------------------------------------------
// K3: exact fp64 recheck over the compacted flagged list (unchanged).
// ---------------------------------------------------------------------------
__global__ __launch_bounds__(256) void recheck(
    const double* __restrict__ qd, const double* __restrict__ kd,
    const int* __restrict__ cnt, const int* __restrict__ list,
    float* __restrict__ star, int* __restrict__ argb) {
  __shared__ double bvS[4];
  __shared__ int biS[4];
  int n = cnt[0];
  int tid = threadIdx.x;
  int lane = tid & 63, wv = tid >> 6;
  for (int idx = blockIdx.x; idx < n; idx += gridDim.x) {
    int e = list[idx];
    int b = e >> 12, j = e & 4095;
    const double* qp = qd + ((size_t)b * HWn + j) * 32;
    double qj[32];
#pragma unroll
    for (int o = 0; o < 32; ++o) qj[o] = qp[o];
    double best = -1.0e300;
    int bi = 1 << 30;
    for (int i = tid; i < HWn; i += 256) {
      const double* kp = kd + ((size_t)b * HWn + i) * 32;
      double s = 0.0;
#pragma unroll
      for (int o = 0; o < 32; ++o) s += kp[o] * qj[o];
      if (s > best) { best = s; bi = i; }
    }
#pragma unroll
    for (int m = 1; m < 64; m <<= 1) {
      double ob = __shfl_xor(best, m, 64);
      int oi = __shfl_xor(bi, m, 64);
      if (ob > best || (ob == best && oi < bi)) { best = ob; bi = oi; }
    }
    if (lane == 0) { bvS[wv] = best; biS[wv] = bi; }
    __syncthreads();
    if (tid == 0) {
#pragma unroll
      for (int w = 1; w < 4; ++w) {
        if (bvS[w] > best || (bvS[w] == best && biS[w] < bi)) {
          best = bvS[w]; bi = biS[w];
        }
      }
      star[(size_t)b * HWn + j] = (float)best;
      argb[(size_t)b * HWn + j] = bi;
    }
    __syncthreads();
  }
}

// ---------------------------------------------------------------------------
// K4: transpose to bf16 pixel-major (unchanged).
// ---------------------------------------------------------------------------
__global__ __launch_bounds__(256) void cat_fx(
    const float* __restrict__ fx, const float* __restrict__ fxh,
    unsigned short* __restrict__ catC, unsigned short* __restrict__ xht) {
  int j0 = blockIdx.x * 64;
  int ci0 = blockIdx.y * 64;
  int b = blockIdx.z >> 1;
  int which = blockIdx.z & 1;
  int tid = threadIdx.x;
  __shared__ unsigned short tile[64][66];

  const float* src = (which == 0) ? fx : fxh;
  for (int u = tid; u < 4096; u += 256) {
    int cl = u >> 6, hw_l = u & 63;
    tile[cl][hw_l] = f2bf(src[((size_t)(b * Cn + ci0 + cl)) * HWn + j0 + hw_l]);
  }
  __syncthreads();
  if (which == 0) {
    for (int u = tid; u < 4096; u += 256) {
      int hw_l = u >> 6, cl = u & 63;
      catC[((size_t)b * ROWS + PADR + j0 + hw_l) * 512 + ci0 + cl] = tile[cl][hw_l];
    }
  } else {
    for (int u = tid; u < 4096; u += 256) {
      int hw_l = u >> 6, cl = u & 63;
      xht[((size_t)b * HWn + j0 + hw_l) * 256 + ci0 + cl] = tile[cl][hw_l];
    }
  }
}

// ---------------------------------------------------------------------------
// K5: v projection as bf16 MFMA GEMM (unchanged).
// ---------------------------------------------------------------------------
__global__ __launch_bounds__(256) void proj_v_mfma(
    const unsigned short* __restrict__ xht, const unsigned short* __restrict__ Wvb,
    const float* __restrict__ bv, unsigned short* __restrict__ vbf) {
  int m0 = blockIdx.x * 128;
  int o0 = blockIdx.y * 128;
  int b = blockIdx.z;
  int tid = threadIdx.x;
  int lane = tid & 63, wv = tid >> 6;
  int wm = wv >> 1, wn = wv & 1;
  int lm = lane & 15, lq = lane >> 4;

  __shared__ __align__(16) unsigned short AS[128 * 32];
  __shared__ __align__(16) unsigned short BS[128 * 32];
  __shared__ __align__(16) unsigned short TS[128 * 136];

  floatx4 acc[4][4];
#pragma unroll
  for (int im = 0; im < 4; ++im)
#pragma unroll
    for (int in = 0; in < 4; ++in) acc[im][in] = (floatx4)0.0f;

  const int srow = lane >> 2, soff = (lane & 3) * 8;
  const unsigned short* ag = Wvb + (size_t)o0 * 256;
  const unsigned short* bg = xht + ((size_t)b * HWn + m0) * 256;

  for (int kc = 0; kc < 256; kc += 32) {
    __syncthreads();
#pragma unroll
    for (int i = 0; i < 2; ++i) {
      int r0 = wv * 32 + i * 16;
      gl_lds16(ag + ((size_t)(r0 + srow)) * 256 + kc + soff, &AS[r0 * 32]);
      gl_lds16(bg + ((size_t)(r0 + srow)) * 256 + kc + soff, &BS[r0 * 32]);
    }
    __syncthreads();

    bf16x8 afr[4];
#pragma unroll
    for (int im = 0; im < 4; ++im)
      afr[im] = *reinterpret_cast<const bf16x8*>(
          &AS[(wm * 64 + im * 16 + lm) * 32 + lq * 8]);
#pragma unroll
    for (int in = 0; in < 4; ++in) {
      bf16x8 bfr = *reinterpret_cast<const bf16x8*>(
          &BS[(wn * 64 + in * 16 + lm) * 32 + lq * 8]);
#pragma unroll
      for (int im = 0; im < 4; ++im)
        acc[im][in] = __builtin_amdgcn_mfma_f32_16x16x32_bf16(
            afr[im], bfr, acc[im][in], 0, 0, 0);
    }
  }

  __syncthreads();
#pragma unroll
  for (int in = 0; in < 4; ++in) {
    int pl = wn * 64 + in * 16 + lm;
#pragma unroll
    for (int im = 0; im < 4; ++im) {
#pragma unroll
      for (int r = 0; r < 4; ++r) {
        int ol = wm * 64 + im * 16 + lq * 4 + r;
        TS[pl * 136 + ol] = f2bf(acc[im][in][r] + bv[o0 + ol]);
      }
    }
  }
  __syncthreads();
  for (int idx = tid; idx < 128 * 16; idx += 256) {
    int p = idx >> 4, ch = idx & 15;
    u16x8 val = *reinterpret_cast<const u16x8*>(&TS[p * 136 + ch * 8]);
    *reinterpret_cast<u16x8*>(
        &vbf[((size_t)b * HWn + m0 + p) * 256 + o0 + ch * 8]) = val;
  }
}

// ---------------------------------------------------------------------------
// K6: gather (unchanged; pad-zero block covers PADR=80 rows each side).
// ---------------------------------------------------------------------------
__global__ __launch_bounds__(256) void gather_cat(
    const unsigned short* __restrict__ vbf, const int* __restrict__ argb,
    unsigned short* __restrict__ catC) {
  int b = blockIdx.y;
  int tid = threadIdx.x;
  if (blockIdx.x == 16) {
    for (int u = tid; u < 2 * PADR * 512; u += 256) {
      int r = u >> 9;
      int rr = (r < PADR) ? r : (HWn + r);
      catC[((size_t)b * ROWS + rr) * 512 + (u & 511)] = 0;
    }
    return;
  }
  __shared__ int ajS[256];
  int j0 = blockIdx.x * 256;
  ajS[tid] = argb[(size_t)b * HWn + j0 + tid];
  __syncthreads();
#pragma unroll 4
  for (int u = tid; u < 256 * 32; u += 256) {
    int pl = u >> 5, ch = u & 31;
    int aj = ajS[pl];
    u16x8 val = *reinterpret_cast<const u16x8*>(
        &vbf[((size_t)b * HWn + aj) * 256 + ch * 8]);
    *reinterpret_cast<u16x8*>(
        &catC[((size_t)b * ROWS + PADR + j0 + pl) * 512 + 256 + ch * 8]) = val;
  }
}

// ---------------------------------------------------------------------------
// K7: conv3x3 implicit GEMM, SPLIT-K over tap-rows (dy). Grid 32x2x12 =
// 768 blocks (3/CU). Each block: 3 taps (fixed dy, dx=-1..1) x 16 kc-steps.
// One B-union stage (144 rows x 32 ci) serves all 3 taps (row-shifted reads)
// -> 48 MFMA per barrier pair, B staging traffic /3. Partial acc -> Pg[g].
// ---------------------------------------------------------------------------
__global__ __launch_bounds__(256) void conv_mfma(
    const unsigned short* __restrict__ catC, const unsigned short* __restrict__ Wfb,
    float* __restrict__ Pg) {
  int m0 = blockIdx.x * 128;
  int o0 = blockIdx.y * 128;
  int bz = blockIdx.z;
  int b = bz / 3, g = bz % 3;      // g = dy+1
  int dy = g - 1;
  int tid = threadIdx.x;
  int lane = tid & 63;
  int wv = tid >> 6;
  int wm = wv >> 1, wn = wv & 1;
  int lm = lane & 15, lq = lane >> 4;
  const bool lane_first = (lm == 0);
  const bool lane_last = (lm == 15);

  __shared__ __align__(16) unsigned short AS[3 * 128 * 32];  // [tap][o][k] 24KB
  __shared__ __align__(16) unsigned short BS[144 * 32];      // [urow][k]    9KB

  floatx4 acc[4][4];
#pragma unroll
  for (int im = 0; im < 4; ++im)
#pragma unroll
    for (int in = 0; in < 4; ++in) acc[im][in] = (floatx4)0.0f;

  const int srow = lane >> 2, soff = (lane & 3) * 8;
  // B union base: rows m0 + dy*64 - 1 + u, u in [0,144)
  const unsigned short* bg =
      catC + ((size_t)b * ROWS + PADR + m0 + dy * 64 - 1) * 512;
  // A: taps g*3 .. g*3+2
  const unsigned short* ag = Wfb + ((size_t)(g * 3) * 256 + o0) * 512;

  for (int kc = 0; kc < 512; kc += 32) {
    __syncthreads();
    if (wv < 3) {
      const unsigned short* at = ag + (size_t)wv * 256 * 512;
#pragma unroll
      for (int s = 0; s < 8; ++s)
        gl_lds16(at + ((size_t)(s * 16 + srow)) * 512 + kc + soff,
                 &AS[(wv * 128 + s * 16) * 32]);
    } else {
#pragma unroll
      for (int s = 0; s < 9; ++s)
        gl_lds16(bg + ((size_t)(s * 16 + srow)) * 512 + kc + soff,
                 &BS[(s * 16) * 32]);
    }
    __syncthreads();

#pragma unroll
    for (int t = 0; t < 3; ++t) {   // t = dx+1
      bf16x8 afr[4];
#pragma unroll
      for (int im = 0; im < 4; ++im)
        afr[im] = *reinterpret_cast<const bf16x8*>(
            &AS[(t * 128 + wm * 64 + im * 16 + lm) * 32 + lq * 8]);
#pragma unroll
      for (int in = 0; in < 4; ++in) {
        int u = wn * 64 + in * 16 + lm + t;   // p + 1 + dx
        u16x8 braw = *reinterpret_cast<const u16x8*>(&BS[u * 32 + lq * 8]);
        if ((t == 0 && in == 0 && lane_first) ||
            (t == 2 && in == 3 && lane_last))
          braw = (u16x8)(unsigned short)0;
        union { u16x8 u8; bf16x8 h; } cvt; cvt.u8 = braw;
#pragma unroll
        for (int im = 0; im < 4; ++im)
          acc[im][in] = __builtin_amdgcn_mfma_f32_16x16x32_bf16(
              afr[im], cvt.h, acc[im][in], 0, 0, 0);
      }
    }
  }

  // store partial accumulators: Pg[g][b][o][p]
  float* P = Pg + ((size_t)(g * Bn + b) * Cn) * HWn;
#pragma unroll
  for (int in = 0; in < 4; ++in) {
    int p = m0 + wn * 64 + in * 16 + lm;
#pragma unroll
    for (int im = 0; im < 4; ++im) {
      int ob = o0 + wm * 64 + im * 16 + lq * 4;
#pragma unroll
      for (int r = 0; r < 4; ++r)
        P[(size_t)(ob + r) * HWn + p] = acc[im][in][r];
    }
  }
}

// ---------------------------------------------------------------------------
// K8: combine: out = fx + (P0+P1+P2 + bf)*S, float4-vectorized.
// ---------------------------------------------------------------------------
__global__ __launch_bounds__(256) void combine(
    const float* __restrict__ Pg, const float* __restrict__ fx,
    const float* __restrict__ bf, const float* __restrict__ star,
    float* __restrict__ out) {
  size_t e = ((size_t)blockIdx.x * 256 + threadIdx.x) * 4;
  int p = (int)(e & 4095);
  int bo = (int)(e >> 12);
  int o = bo & 255, b = bo >> 8;
  const size_t gs = (size_t)Bn * Cn * HWn;
  floatx4 a = *reinterpret_cast<const floatx4*>(Pg + e) +
              *reinterpret_cast<const floatx4*>(Pg + gs + e) +
              *reinterpret_cast<const floatx4*>(Pg + 2 * gs + e);
  float bias = bf[o];
  floatx4 s = *reinterpret_cast<const floatx4*>(star + (size_t)b * HWn + p);
  floatx4 f = *reinterpret_cast<const floatx4*>(fx + e);
  floatx4 r;
#pragma unroll
  for (int i = 0; i < 4; ++i) r[i] = f[i] + (a[i] + bias) * s[i];
  *reinterpret_cast<floatx4*>(out + e) = r;
}

// ---------------------------------------------------------------------------
extern "C" void kernel_launch(void* const* d_in, const int* in_sizes, int n_in,
                              void* d_out, int out_size, void* d_ws, size_t ws_size,
                              hipStream_t stream) {
  const float* front_x   = (const float*)d_in[0];
  const float* cross_x   = (const float*)d_in[1];
  const float* front_hat = (const float*)d_in[2];
  const float* Wq = (const float*)d_in[3];
  const float* bq = (const float*)d_in[4];
  const float* Wk = (const float*)d_in[5];
  const float* bk = (const float*)d_in[6];
  const float* Wv = (const float*)d_in[7];
  const float* bv = (const float*)d_in[8];
  const float* Wf = (const float*)d_in[9];
  const float* bf = (const float*)d_in[10];
  float* out = (float*)d_out;

  char* ws = (char*)d_ws;
  size_t off = 0;
  auto alloc = [&](size_t bytes) -> void* {
    void* p = (void*)(ws + off);
    off += (bytes + 255) & ~(size_t)255;
    return p;
  };
  double* Wqt = (double*)alloc(8192 * sizeof(double));
  double* Wkt = (double*)alloc(8192 * sizeof(double));
  double* bqd = (double*)alloc(32 * sizeof(double));
  double* bkd = (double*)alloc(32 * sizeof(double));
  unsigned short* Wvb = (unsigned short*)alloc(65536 * sizeof(unsigned short));
  unsigned short* Wfb = (unsigned short*)alloc((size_t)9 * 256 * 512 * sizeof(unsigned short));
  double* qd  = (double*)alloc((size_t)Bn * HWn * C8 * sizeof(double));
  double* kd  = (double*)alloc((size_t)Bn * HWn * C8 * sizeof(double));
  unsigned short* qhi = (unsigned short*)alloc((size_t)Bn * HWn * C8 * 2);
  unsigned short* qlo = (unsigned short*)alloc((size_t)Bn * HWn * C8 * 2);
  unsigned short* khi = (unsigned short*)alloc((size_t)Bn * HWn * C8 * 2);
  unsigned short* klo = (unsigned short*)alloc((size_t)Bn * HWn * C8 * 2);
  float*  star = (float*)alloc((size_t)Bn * HWn * sizeof(float));
  int*    argb = (int*)alloc((size_t)Bn * HWn * sizeof(int));
  int*    cnt  = (int*)alloc(256);
  int*    list = (int*)alloc((size_t)Bn * HWn * sizeof(int));
  unsigned short* xht = (unsigned short*)alloc((size_t)Bn * HWn * 256 * 2);
  unsigned short* vbf = (unsigned short*)alloc((size_t)Bn * HWn * 256 * 2);
  unsigned short* catC = (unsigned short*)alloc((size_t)Bn * ROWS * 512 * sizeof(unsigned short));
  float* Pg = (float*)alloc((size_t)3 * Bn * Cn * HWn * sizeof(float));  // 50 MB

  prep_w<<<dim3((9 * 256 * 512 + 255) / 256), dim3(256), 0, stream>>>(
      Wq, bq, Wk, bk, Wv, Wf, Wqt, bqd, Wkt, bkd, Wvb, Wfb, cnt);

  proj_qk<<<dim3(HWn / 64, Bn, 2), dim3(1024), 0, stream>>>(
      cross_x, front_x, Wqt, bqd, Wkt, bkd, qd, kd, qhi, qlo, khi, klo);

  energy_approx<<<dim3(HWn / 64, Bn), dim3(1024), 0, stream>>>(
      khi, klo, qhi, qlo, star, argb, cnt, list);

  recheck<<<dim3(256), dim3(256), 0, stream>>>(qd, kd, cnt, list, star, argb);

  cat_fx<<<dim3(HWn / 64, Cn / 64, Bn * 2), dim3(256), 0, stream>>>(
      front_x, front_hat, catC, xht);

  proj_v_mfma<<<dim3(HWn / 128, Cn / 128, Bn), dim3(256), 0, stream>>>(
      xht, Wvb, bv, vbf);

  gather_cat<<<dim3(HWn / 256 + 1, Bn), dim3(256), 0, stream>>>(vbf, argb, catC);

  conv_mfma<<<dim3(HWn / 128, Cn / 128, Bn * 3), dim3(256), 0, stream>>>(
      catC, Wfb, Pg);

  combine<<<dim3((Bn * Cn * HWn / 4) / 256), dim3(256), 0, stream>>>(
      Pg, front_x, bf, star, out);
}

// Round 9
// 270.253 us; speedup vs baseline: 2.6762x; 1.2609x over previous
//
#include <hip/hip_runtime.h>

#define Bn 4
#define Cn 256
#define C8 32
#define Hn 64
#define Wn 64
#define HWn 4096
#define PADR 80
#define ROWS (HWn + 2 * PADR)   // 4256 padded pixel-rows per batch
#define MARGIN 6e-3f

typedef __bf16 bf16x8 __attribute__((ext_vector_type(8)));
typedef float floatx4 __attribute__((ext_vector_type(4)));
typedef unsigned short u16x8 __attribute__((ext_vector_type(8)));

__device__ __forceinline__ unsigned short f2bf(float f) {
  union { float f; unsigned int u; } c; c.f = f;
  unsigned int u = c.u;
  return (unsigned short)((u + 0x7FFFu + ((u >> 16) & 1u)) >> 16);  // RNE
}
__device__ __forceinline__ float bf2f(unsigned short h) {
  union { unsigned int u; float f; } c; c.u = ((unsigned int)h) << 16;
  return c.f;
}
__device__ __forceinline__ void gl_lds16(const void* g, void* l) {
  __builtin_amdgcn_global_load_lds(
      (__attribute__((address_space(1))) void*)(uintptr_t)g,
      (__attribute__((address_space(3))) void*)(uintptr_t)l, 16, 0, 0);
}

// ---------------------------------------------------------------------------
// K0: weight prep + zero flagged-query counter.
//   Wq/Wk -> fp32 transposed [c][32]; Wv -> bf16 [o][c]; Wf -> bf16 [tap][o][ci]
// ---------------------------------------------------------------------------
__global__ void prep_w(const float* __restrict__ Wq, const float* __restrict__ Wk,
                       const float* __restrict__ Wv, const float* __restrict__ Wf,
                       float* __restrict__ Wqf, float* __restrict__ Wkf,
                       unsigned short* __restrict__ Wvb, unsigned short* __restrict__ Wfb,
                       int* __restrict__ cnt) {
  size_t t = (size_t)blockIdx.x * 256 + threadIdx.x;
  if (t == 0) cnt[0] = 0;
  if (t < 8192) {
    int o = (int)(t / 256), c = (int)(t % 256);
    Wqf[(size_t)c * 32 + o] = Wq[t];
    Wkf[(size_t)c * 32 + o] = Wk[t];
  }
  if (t < 65536) Wvb[t] = f2bf(Wv[t]);   // [o][c] row-major already
  if (t < (size_t)9 * 256 * 512) {
    int tap = (int)(t / (256 * 512));
    int rem = (int)(t % (256 * 512));
    int o = rem / 512, ci = rem % 512;
    Wfb[t] = f2bf(Wf[((size_t)o * 512 + ci) * 9 + tap]);
  }
}

// ---------------------------------------------------------------------------
// K1: q/k projection in FP32 (reference precision). 1024-thr blocks, 16 waves
// = (o-slice 0..3) x (c-chunk 0..3). Weights staged in LDS (32KB, broadcast
// ds_read_b128); part buffer fp32 (24KB) -> 56KB/block, 2 blocks/CU =
// 32 waves/CU. Unroll 16 keeps ~16 x-loads in flight per wave.
// Ground truth for argmax = fp64 dot over these fp32 q,k (see recheck).
// ---------------------------------------------------------------------------
__global__ __launch_bounds__(1024) void proj_qk(
    const float* __restrict__ cross_x, const float* __restrict__ front_x,
    const float* __restrict__ Wqf, const float* __restrict__ bq,
    const float* __restrict__ Wkf, const float* __restrict__ bk,
    float* __restrict__ qf, float* __restrict__ kf,
    unsigned short* __restrict__ qhi, unsigned short* __restrict__ qlo,
    unsigned short* __restrict__ khi, unsigned short* __restrict__ klo) {
  int tid = threadIdx.x;
  int lane = tid & 63, wv = tid >> 6;    // 16 waves
  int slice = wv & 3;                    // o-slice (8 o each)
  int chunk = wv >> 2;                   // c-chunk (64 c each)
  int j = blockIdx.x * 64 + lane;
  int b = blockIdx.y;
  int z = blockIdx.z;
  const float* x = (z == 0) ? cross_x : front_x;
  const float* Wg = (z == 0) ? Wqf : Wkf;
  const float* bd = (z == 0) ? bq : bk;
  float* outp = (z == 0) ? qf : kf;
  unsigned short* hip_ = (z == 0) ? qhi : khi;
  unsigned short* lop_ = (z == 0) ? qlo : klo;
  int o0 = slice * 8;
  int c0 = chunk * 64;

  __shared__ __align__(16) float Wl[8192];        // [c][32] fp32, 32KB
  __shared__ float part[3 * 4 * 8 * 64];          // [chunk-1][slice][o][lane] 24KB

  for (int u = tid; u < 8192; u += 1024) Wl[u] = Wg[u];
  __syncthreads();

  const float* xb = x + (size_t)b * Cn * HWn + j;
  floatx4 a0 = (floatx4)0.0f, a1 = (floatx4)0.0f;
#pragma unroll 16
  for (int c = c0; c < c0 + 64; ++c) {
    float xv = xb[(size_t)c * HWn];
    floatx4 wa = *reinterpret_cast<const floatx4*>(&Wl[c * 32 + o0]);      // broadcast
    floatx4 wb = *reinterpret_cast<const floatx4*>(&Wl[c * 32 + o0 + 4]);
    a0 += wa * xv;
    a1 += wb * xv;
  }
  if (chunk > 0) {
    float* dst = &part[(((chunk - 1) * 4 + slice) * 8) * 64];
#pragma unroll
    for (int o = 0; o < 4; ++o) { dst[o * 64 + lane] = a0[o]; dst[(o + 4) * 64 + lane] = a1[o]; }
  }
  __syncthreads();
  if (chunk != 0) return;
#pragma unroll
  for (int q = 0; q < 3; ++q) {
    const float* src = &part[((q * 4 + slice) * 8) * 64];
#pragma unroll
    for (int o = 0; o < 4; ++o) { a0[o] += src[o * 64 + lane]; a1[o] += src[(o + 4) * 64 + lane]; }
  }
  float acc[8];
#pragma unroll
  for (int o = 0; o < 4; ++o) { acc[o] = a0[o] + bd[o0 + o]; acc[o + 4] = a1[o] + bd[o0 + 4 + o]; }

  float* op = outp + ((size_t)b * HWn + j) * C8 + o0;
  u16x8 hv, lv;
#pragma unroll
  for (int o = 0; o < 8; ++o) {
    op[o] = acc[o];
    unsigned short h = f2bf(acc[o]);
    hv[o] = h;
    lv[o] = f2bf(acc[o] - bf2f(h));
  }
  *reinterpret_cast<u16x8*>(hip_ + ((size_t)b * HWn + j) * C8 + o0) = hv;
  *reinterpret_cast<u16x8*>(lop_ + ((size_t)b * HWn + j) * C8 + o0) = lv;
}

// ---------------------------------------------------------------------------
// K2: approximate energy via split-bf16 MFMA (unchanged from R6).
// ---------------------------------------------------------------------------
__global__ __launch_bounds__(1024) void energy_approx(
    const unsigned short* __restrict__ khi, const unsigned short* __restrict__ klo,
    const unsigned short* __restrict__ qhi, const unsigned short* __restrict__ qlo,
    float* __restrict__ star, int* __restrict__ argb,
    int* __restrict__ cnt, int* __restrict__ list) {
  int b = blockIdx.y;
  int j0 = blockIdx.x * 64;
  int tid = threadIdx.x;
  int lane = tid & 63, wv = tid >> 6;   // wv 0..15
  int lm = lane & 15, lq = lane >> 4;

  __shared__ float bv1S[16][64];
  __shared__ int   bi1S[16][64];
  __shared__ float bv2S[16][64];

  bf16x8 qh[4], ql[4];
#pragma unroll
  for (int s = 0; s < 4; ++s) {
    int j = j0 + s * 16 + lm;
    qh[s] = *reinterpret_cast<const bf16x8*>(qhi + ((size_t)b * HWn + j) * 32 + lq * 8);
    ql[s] = *reinterpret_cast<const bf16x8*>(qlo + ((size_t)b * HWn + j) * 32 + lq * 8);
  }
  const unsigned short* kh_base = khi + (size_t)b * HWn * 32 + lq * 8;
  const unsigned short* kl_base = klo + (size_t)b * HWn * 32 + lq * 8;

  float b1[4], b2[4];
  int i1[4];
#pragma unroll
  for (int s = 0; s < 4; ++s) { b1[s] = -3.0e38f; b2[s] = -3.0e38f; i1[s] = 0; }

  int ibase = wv * 256;
#pragma unroll 2
  for (int it = 0; it < 16; ++it) {
    int i0 = ibase + it * 16;
    bf16x8 ah = *reinterpret_cast<const bf16x8*>(kh_base + (size_t)(i0 + lm) * 32);
    bf16x8 al = *reinterpret_cast<const bf16x8*>(kl_base + (size_t)(i0 + lm) * 32);
#pragma unroll
    for (int s = 0; s < 4; ++s) {
      floatx4 acc = (floatx4)0.0f;
      acc = __builtin_amdgcn_mfma_f32_16x16x32_bf16(ah, qh[s], acc, 0, 0, 0);
      acc = __builtin_amdgcn_mfma_f32_16x16x32_bf16(ah, ql[s], acc, 0, 0, 0);
      acc = __builtin_amdgcn_mfma_f32_16x16x32_bf16(al, qh[s], acc, 0, 0, 0);
      float m4 = fmaxf(fmaxf(acc[0], acc[1]), fmaxf(acc[2], acc[3]));
      if (m4 > b1[s]) {
        int ib = i0 + lq * 4;
#pragma unroll
        for (int r = 0; r < 4; ++r) {
          float s2 = acc[r];
          if (s2 > b1[s]) { b2[s] = b1[s]; b1[s] = s2; i1[s] = ib + r; }
          else b2[s] = fmaxf(b2[s], s2);
        }
      } else {
        b2[s] = fmaxf(b2[s], m4);
      }
    }
  }
#pragma unroll
  for (int s = 0; s < 4; ++s) {
#pragma unroll
    for (int m = 16; m <= 32; m <<= 1) {
      float ob1 = __shfl_xor(b1[s], m, 64);
      int oi1 = __shfl_xor(i1[s], m, 64);
      float ob2 = __shfl_xor(b2[s], m, 64);
      float c2;
      if (ob1 > b1[s] || (ob1 == b1[s] && oi1 < i1[s])) {
        c2 = fmaxf(b1[s], ob2);
        b1[s] = ob1; i1[s] = oi1;
      } else {
        c2 = fmaxf(ob1, b2[s]);
      }
      b2[s] = c2;
    }
    if (lq == 0) {
      bv1S[wv][s * 16 + lm] = b1[s];
      bi1S[wv][s * 16 + lm] = i1[s];
      bv2S[wv][s * 16 + lm] = b2[s];
    }
  }
  __syncthreads();
  if (tid < 64) {
    float B1 = bv1S[0][tid];
    int I1 = bi1S[0][tid];
    float B2 = bv2S[0][tid];
#pragma unroll
    for (int w = 1; w < 16; ++w) {
      float v1 = bv1S[w][tid];
      int ii = bi1S[w][tid];
      float v2 = bv2S[w][tid];
      if (v1 > B1) { B2 = fmaxf(B1, v2); B1 = v1; I1 = ii; }
      else B2 = fmaxf(B2, v1);
    }
    size_t o = (size_t)b * HWn + j0 + tid;
    star[o] = B1;
    argb[o] = I1;
    if (B1 - B2 < MARGIN) {
      int slot = atomicAdd(cnt, 1);
      list[slot] = (b << 12) | (j0 + tid);
    }
  }
}

// ---------------------------------------------------------------------------
// K3: recheck — fp64 accumulation over fp32 q,k (ground truth), compacted list.
// ---------------------------------------------------------------------------
__global__ __launch_bounds__(256) void recheck(
    const float* __restrict__ qf, const float* __restrict__ kf,
    const int* __restrict__ cnt, const int* __restrict__ list,
    float* __restrict__ star, int* __restrict__ argb) {
  __shared__ double bvS[4];
  __shared__ int biS[4];
  int n = cnt[0];
  int tid = threadIdx.x;
  int lane = tid & 63, wv = tid >> 6;
  for (int idx = blockIdx.x; idx < n; idx += gridDim.x) {
    int e = list[idx];
    int b = e >> 12, j = e & 4095;
    const float* qp = qf + ((size_t)b * HWn + j) * 32;
    double qj[32];
#pragma unroll
    for (int o = 0; o < 32; ++o) qj[o] = (double)qp[o];
    double best = -1.0e300;
    int bi = 1 << 30;
    for (int i = tid; i < HWn; i += 256) {
      const float* kp = kf + ((size_t)b * HWn + i) * 32;
      double s = 0.0;
#pragma unroll
      for (int o = 0; o < 32; ++o) s += (double)kp[o] * qj[o];
      if (s > best) { best = s; bi = i; }
    }
#pragma unroll
    for (int m = 1; m < 64; m <<= 1) {
      double ob = __shfl_xor(best, m, 64);
      int oi = __shfl_xor(bi, m, 64);
      if (ob > best || (ob == best && oi < bi)) { best = ob; bi = oi; }
    }
    if (lane == 0) { bvS[wv] = best; biS[wv] = bi; }
    __syncthreads();
    if (tid == 0) {
#pragma unroll
      for (int w = 1; w < 4; ++w) {
        if (bvS[w] > best || (bvS[w] == best && biS[w] < bi)) {
          best = bvS[w]; bi = biS[w];
        }
      }
      star[(size_t)b * HWn + j] = (float)best;
      argb[(size_t)b * HWn + j] = bi;
    }
    __syncthreads();
  }
}

// ---------------------------------------------------------------------------
// K4: transpose to bf16 pixel-major (unchanged).
// ---------------------------------------------------------------------------
__global__ __launch_bounds__(256) void cat_fx(
    const float* __restrict__ fx, const float* __restrict__ fxh,
    unsigned short* __restrict__ catC, unsigned short* __restrict__ xht) {
  int j0 = blockIdx.x * 64;
  int ci0 = blockIdx.y * 64;
  int b = blockIdx.z >> 1;
  int which = blockIdx.z & 1;
  int tid = threadIdx.x;
  __shared__ unsigned short tile[64][66];

  const float* src = (which == 0) ? fx : fxh;
  for (int u = tid; u < 4096; u += 256) {
    int cl = u >> 6, hw_l = u & 63;
    tile[cl][hw_l] = f2bf(src[((size_t)(b * Cn + ci0 + cl)) * HWn + j0 + hw_l]);
  }
  __syncthreads();
  if (which == 0) {
    for (int u = tid; u < 4096; u += 256) {
      int hw_l = u >> 6, cl = u & 63;
      catC[((size_t)b * ROWS + PADR + j0 + hw_l) * 512 + ci0 + cl] = tile[cl][hw_l];
    }
  } else {
    for (int u = tid; u < 4096; u += 256) {
      int hw_l = u >> 6, cl = u & 63;
      xht[((size_t)b * HWn + j0 + hw_l) * 256 + ci0 + cl] = tile[cl][hw_l];
    }
  }
}

// ---------------------------------------------------------------------------
// K5: v projection as bf16 MFMA GEMM (unchanged).
// ---------------------------------------------------------------------------
__global__ __launch_bounds__(256) void proj_v_mfma(
    const unsigned short* __restrict__ xht, const unsigned short* __restrict__ Wvb,
    const float* __restrict__ bv, unsigned short* __restrict__ vbf) {
  int m0 = blockIdx.x * 128;
  int o0 = blockIdx.y * 128;
  int b = blockIdx.z;
  int tid = threadIdx.x;
  int lane = tid & 63, wv = tid >> 6;
  int wm = wv >> 1, wn = wv & 1;
  int lm = lane & 15, lq = lane >> 4;

  __shared__ __align__(16) unsigned short AS[128 * 32];
  __shared__ __align__(16) unsigned short BS[128 * 32];
  __shared__ __align__(16) unsigned short TS[128 * 136];

  floatx4 acc[4][4];
#pragma unroll
  for (int im = 0; im < 4; ++im)
#pragma unroll
    for (int in = 0; in < 4; ++in) acc[im][in] = (floatx4)0.0f;

  const int srow = lane >> 2, soff = (lane & 3) * 8;
  const unsigned short* ag = Wvb + (size_t)o0 * 256;
  const unsigned short* bg = xht + ((size_t)b * HWn + m0) * 256;

  for (int kc = 0; kc < 256; kc += 32) {
    __syncthreads();
#pragma unroll
    for (int i = 0; i < 2; ++i) {
      int r0 = wv * 32 + i * 16;
      gl_lds16(ag + ((size_t)(r0 + srow)) * 256 + kc + soff, &AS[r0 * 32]);
      gl_lds16(bg + ((size_t)(r0 + srow)) * 256 + kc + soff, &BS[r0 * 32]);
    }
    __syncthreads();

    bf16x8 afr[4];
#pragma unroll
    for (int im = 0; im < 4; ++im)
      afr[im] = *reinterpret_cast<const bf16x8*>(
          &AS[(wm * 64 + im * 16 + lm) * 32 + lq * 8]);
#pragma unroll
    for (int in = 0; in < 4; ++in) {
      bf16x8 bfr = *reinterpret_cast<const bf16x8*>(
          &BS[(wn * 64 + in * 16 + lm) * 32 + lq * 8]);
#pragma unroll
      for (int im = 0; im < 4; ++im)
        acc[im][in] = __builtin_amdgcn_mfma_f32_16x16x32_bf16(
            afr[im], bfr, acc[im][in], 0, 0, 0);
    }
  }

  __syncthreads();
#pragma unroll
  for (int in = 0; in < 4; ++in) {
    int pl = wn * 64 + in * 16 + lm;
#pragma unroll
    for (int im = 0; im < 4; ++im) {
#pragma unroll
      for (int r = 0; r < 4; ++r) {
        int ol = wm * 64 + im * 16 + lq * 4 + r;
        TS[pl * 136 + ol] = f2bf(acc[im][in][r] + bv[o0 + ol]);
      }
    }
  }
  __syncthreads();
  for (int idx = tid; idx < 128 * 16; idx += 256) {
    int p = idx >> 4, ch = idx & 15;
    u16x8 val = *reinterpret_cast<const u16x8*>(&TS[p * 136 + ch * 8]);
    *reinterpret_cast<u16x8*>(
        &vbf[((size_t)b * HWn + m0 + p) * 256 + o0 + ch * 8]) = val;
  }
}

// ---------------------------------------------------------------------------
// K6: gather (unchanged; pad-zero block covers PADR rows each side).
// ---------------------------------------------------------------------------
__global__ __launch_bounds__(256) void gather_cat(
    const unsigned short* __restrict__ vbf, const int* __restrict__ argb,
    unsigned short* __restrict__ catC) {
  int b = blockIdx.y;
  int tid = threadIdx.x;
  if (blockIdx.x == 16) {
    for (int u = tid; u < 2 * PADR * 512; u += 256) {
      int r = u >> 9;
      int rr = (r < PADR) ? r : (HWn + r);
      catC[((size_t)b * ROWS + rr) * 512 + (u & 511)] = 0;
    }
    return;
  }
  __shared__ int ajS[256];
  int j0 = blockIdx.x * 256;
  ajS[tid] = argb[(size_t)b * HWn + j0 + tid];
  __syncthreads();
#pragma unroll 4
  for (int u = tid; u < 256 * 32; u += 256) {
    int pl = u >> 5, ch = u & 31;
    int aj = ajS[pl];
    u16x8 val = *reinterpret_cast<const u16x8*>(
        &vbf[((size_t)b * HWn + aj) * 256 + ch * 8]);
    *reinterpret_cast<u16x8*>(
        &catC[((size_t)b * ROWS + PADR + j0 + pl) * 512 + 256 + ch * 8]) = val;
  }
}

// ---------------------------------------------------------------------------
// K7: conv3x3 implicit GEMM, split-K over tap-rows (unchanged from R8).
// ---------------------------------------------------------------------------
__global__ __launch_bounds__(256) void conv_mfma(
    const unsigned short* __restrict__ catC, const unsigned short* __restrict__ Wfb,
    float* __restrict__ Pg) {
  int m0 = blockIdx.x * 128;
  int o0 = blockIdx.y * 128;
  int bz = blockIdx.z;
  int b = bz / 3, g = bz % 3;      // g = dy+1
  int dy = g - 1;
  int tid = threadIdx.x;
  int lane = tid & 63;
  int wv = tid >> 6;
  int wm = wv >> 1, wn = wv & 1;
  int lm = lane & 15, lq = lane >> 4;
  const bool lane_first = (lm == 0);
  const bool lane_last = (lm == 15);

  __shared__ __align__(16) unsigned short AS[3 * 128 * 32];  // [tap][o][k] 24KB
  __shared__ __align__(16) unsigned short BS[144 * 32];      // [urow][k]    9KB

  floatx4 acc[4][4];
#pragma unroll
  for (int im = 0; im < 4; ++im)
#pragma unroll
    for (int in = 0; in < 4; ++in) acc[im][in] = (floatx4)0.0f;

  const int srow = lane >> 2, soff = (lane & 3) * 8;
  const unsigned short* bg =
      catC + ((size_t)b * ROWS + PADR + m0 + dy * 64 - 1) * 512;
  const unsigned short* ag = Wfb + ((size_t)(g * 3) * 256 + o0) * 512;

  for (int kc = 0; kc < 512; kc += 32) {
    __syncthreads();
    if (wv < 3) {
      const unsigned short* at = ag + (size_t)wv * 256 * 512;
#pragma unroll
      for (int s = 0; s < 8; ++s)
        gl_lds16(at + ((size_t)(s * 16 + srow)) * 512 + kc + soff,
                 &AS[(wv * 128 + s * 16) * 32]);
    } else {
#pragma unroll
      for (int s = 0; s < 9; ++s)
        gl_lds16(bg + ((size_t)(s * 16 + srow)) * 512 + kc + soff,
                 &BS[(s * 16) * 32]);
    }
    __syncthreads();

#pragma unroll
    for (int t = 0; t < 3; ++t) {   // t = dx+1
      bf16x8 afr[4];
#pragma unroll
      for (int im = 0; im < 4; ++im)
        afr[im] = *reinterpret_cast<const bf16x8*>(
            &AS[(t * 128 + wm * 64 + im * 16 + lm) * 32 + lq * 8]);
#pragma unroll
      for (int in = 0; in < 4; ++in) {
        int u = wn * 64 + in * 16 + lm + t;   // p + 1 + dx
        u16x8 braw = *reinterpret_cast<const u16x8*>(&BS[u * 32 + lq * 8]);
        if ((t == 0 && in == 0 && lane_first) ||
            (t == 2 && in == 3 && lane_last))
          braw = (u16x8)(unsigned short)0;
        union { u16x8 u8; bf16x8 h; } cvt; cvt.u8 = braw;
#pragma unroll
        for (int im = 0; im < 4; ++im)
          acc[im][in] = __builtin_amdgcn_mfma_f32_16x16x32_bf16(
              afr[im], cvt.h, acc[im][in], 0, 0, 0);
      }
    }
  }

  float* P = Pg + ((size_t)(g * Bn + b) * Cn) * HWn;
#pragma unroll
  for (int in = 0; in < 4; ++in) {
    int p = m0 + wn * 64 + in * 16 + lm;
#pragma unroll
    for (int im = 0; im < 4; ++im) {
      int ob = o0 + wm * 64 + im * 16 + lq * 4;
#pragma unroll
      for (int r = 0; r < 4; ++r)
        P[(size_t)(ob + r) * HWn + p] = acc[im][in][r];
    }
  }
}

// ---------------------------------------------------------------------------
// K8: combine: out = fx + (P0+P1+P2 + bf)*S, float4-vectorized (unchanged).
// ---------------------------------------------------------------------------
__global__ __launch_bounds__(256) void combine(
    const float* __restrict__ Pg, const float* __restrict__ fx,
    const float* __restrict__ bf, const float* __restrict__ star,
    float* __restrict__ out) {
  size_t e = ((size_t)blockIdx.x * 256 + threadIdx.x) * 4;
  int p = (int)(e & 4095);
  int bo = (int)(e >> 12);
  int o = bo & 255, b = bo >> 8;
  const size_t gs = (size_t)Bn * Cn * HWn;
  floatx4 a = *reinterpret_cast<const floatx4*>(Pg + e) +
              *reinterpret_cast<const floatx4*>(Pg + gs + e) +
              *reinterpret_cast<const floatx4*>(Pg + 2 * gs + e);
  float bias = bf[o];
  floatx4 s = *reinterpret_cast<const floatx4*>(star + (size_t)b * HWn + p);
  floatx4 f = *reinterpret_cast<const floatx4*>(fx + e);
  floatx4 r;
#pragma unroll
  for (int i = 0; i < 4; ++i) r[i] = f[i] + (a[i] + bias) * s[i];
  *reinterpret_cast<floatx4*>(out + e) = r;
}

// ---------------------------------------------------------------------------
extern "C" void kernel_launch(void* const* d_in, const int* in_sizes, int n_in,
                              void* d_out, int out_size, void* d_ws, size_t ws_size,
                              hipStream_t stream) {
  const float* front_x   = (const float*)d_in[0];
  const float* cross_x   = (const float*)d_in[1];
  const float* front_hat = (const float*)d_in[2];
  const float* Wq = (const float*)d_in[3];
  const float* bq = (const float*)d_in[4];
  const float* Wk = (const float*)d_in[5];
  const float* bk = (const float*)d_in[6];
  const float* Wv = (const float*)d_in[7];
  const float* bv = (const float*)d_in[8];
  const float* Wf = (const float*)d_in[9];
  const float* bf = (const float*)d_in[10];
  float* out = (float*)d_out;

  char* ws = (char*)d_ws;
  size_t off = 0;
  auto alloc = [&](size_t bytes) -> void* {
    void* p = (void*)(ws + off);
    off += (bytes + 255) & ~(size_t)255;
    return p;
  };
  float* Wqf = (float*)alloc(8192 * sizeof(float));
  float* Wkf = (float*)alloc(8192 * sizeof(float));
  unsigned short* Wvb = (unsigned short*)alloc(65536 * sizeof(unsigned short));
  unsigned short* Wfb = (unsigned short*)alloc((size_t)9 * 256 * 512 * sizeof(unsigned short));
  float* qf  = (float*)alloc((size_t)Bn * HWn * C8 * sizeof(float));
  float* kf  = (float*)alloc((size_t)Bn * HWn * C8 * sizeof(float));
  unsigned short* qhi = (unsigned short*)alloc((size_t)Bn * HWn * C8 * 2);
  unsigned short* qlo = (unsigned short*)alloc((size_t)Bn * HWn * C8 * 2);
  unsigned short* khi = (unsigned short*)alloc((size_t)Bn * HWn * C8 * 2);
  unsigned short* klo = (unsigned short*)alloc((size_t)Bn * HWn * C8 * 2);
  float*  star = (float*)alloc((size_t)Bn * HWn * sizeof(float));
  int*    argb = (int*)alloc((size_t)Bn * HWn * sizeof(int));
  int*    cnt  = (int*)alloc(256);
  int*    list = (int*)alloc((size_t)Bn * HWn * sizeof(int));
  unsigned short* xht = (unsigned short*)alloc((size_t)Bn * HWn * 256 * 2);
  unsigned short* vbf = (unsigned short*)alloc((size_t)Bn * HWn * 256 * 2);
  unsigned short* catC = (unsigned short*)alloc((size_t)Bn * ROWS * 512 * sizeof(unsigned short));
  float* Pg = (float*)alloc((size_t)3 * Bn * Cn * HWn * sizeof(float));  // 50 MB

  prep_w<<<dim3((9 * 256 * 512 + 255) / 256), dim3(256), 0, stream>>>(
      Wq, Wk, Wv, Wf, Wqf, Wkf, Wvb, Wfb, cnt);

  proj_qk<<<dim3(HWn / 64, Bn, 2), dim3(1024), 0, stream>>>(
      cross_x, front_x, Wqf, bq, Wkf, bk, qf, kf, qhi, qlo, khi, klo);

  energy_approx<<<dim3(HWn / 64, Bn), dim3(1024), 0, stream>>>(
      khi, klo, qhi, qlo, star, argb, cnt, list);

  recheck<<<dim3(256), dim3(256), 0, stream>>>(qf, kf, cnt, list, star, argb);

  cat_fx<<<dim3(HWn / 64, Cn / 64, Bn * 2), dim3(256), 0, stream>>>(
      front_x, front_hat, catC, xht);

  proj_v_mfma<<<dim3(HWn / 128, Cn / 128, Bn), dim3(256), 0, stream>>>(
      xht, Wvb, bv, vbf);

  gather_cat<<<dim3(HWn / 256 + 1, Bn), dim3(256), 0, stream>>>(vbf, argb, catC);

  conv_mfma<<<dim3(HWn / 128, Cn / 128, Bn * 3), dim3(256), 0, stream>>>(
      catC, Wfb, Pg);

  combine<<<dim3((Bn * Cn * HWn / 4) / 256), dim3(256), 0, stream>>>(
      Pg, front_x, bf, star, out);
}

// Round 10
// 259.345 us; speedup vs baseline: 2.7888x; 1.0421x over previous
//
#include <hip/hip_runtime.h>

#define Bn 4
#define Cn 256
#define C8 32
#define Hn 64
#define Wn 64
#define HWn 4096
#define PADR 80
#define ROWS (HWn + 2 * PADR)   // 4256 padded pixel-rows per batch
#define MARGIN 6e-3f

typedef __bf16 bf16x8 __attribute__((ext_vector_type(8)));
typedef float floatx4 __attribute__((ext_vector_type(4)));
typedef unsigned short u16x8 __attribute__((ext_vector_type(8)));

__device__ __forceinline__ unsigned short f2bf(float f) {
  union { float f; unsigned int u; } c; c.f = f;
  unsigned int u = c.u;
  return (unsigned short)((u + 0x7FFFu + ((u >> 16) & 1u)) >> 16);  // RNE
}
__device__ __forceinline__ float bf2f(unsigned short h) {
  union { unsigned int u; float f; } c; c.u = ((unsigned int)h) << 16;
  return c.f;
}
__device__ __forceinline__ void gl_lds16(const void* g, void* l) {
  __builtin_amdgcn_global_load_lds(
      (__attribute__((address_space(1))) void*)(uintptr_t)g,
      (__attribute__((address_space(3))) void*)(uintptr_t)l, 16, 0, 0);
}

// ---------------------------------------------------------------------------
// K0: weight prep + zero flagged-query counter (unchanged).
// ---------------------------------------------------------------------------
__global__ void prep_w(const float* __restrict__ Wq, const float* __restrict__ Wk,
                       const float* __restrict__ Wv, const float* __restrict__ Wf,
                       float* __restrict__ Wqf, float* __restrict__ Wkf,
                       unsigned short* __restrict__ Wvb, unsigned short* __restrict__ Wfb,
                       int* __restrict__ cnt) {
  size_t t = (size_t)blockIdx.x * 256 + threadIdx.x;
  if (t == 0) cnt[0] = 0;
  if (t < 8192) {
    int o = (int)(t / 256), c = (int)(t % 256);
    Wqf[(size_t)c * 32 + o] = Wq[t];
    Wkf[(size_t)c * 32 + o] = Wk[t];
  }
  if (t < 65536) Wvb[t] = f2bf(Wv[t]);   // [o][c] row-major already
  if (t < (size_t)9 * 256 * 512) {
    int tap = (int)(t / (256 * 512));
    int rem = (int)(t % (256 * 512));
    int o = rem / 512, ci = rem % 512;
    Wfb[t] = f2bf(Wf[((size_t)o * 512 + ci) * 9 + tap]);
  }
}

// ---------------------------------------------------------------------------
// K1: q/k projection in FP32 (unchanged from R9).
// ---------------------------------------------------------------------------
__global__ __launch_bounds__(1024) void proj_qk(
    const float* __restrict__ cross_x, const float* __restrict__ front_x,
    const float* __restrict__ Wqf, const float* __restrict__ bq,
    const float* __restrict__ Wkf, const float* __restrict__ bk,
    float* __restrict__ qf, float* __restrict__ kf,
    unsigned short* __restrict__ qhi, unsigned short* __restrict__ qlo,
    unsigned short* __restrict__ khi, unsigned short* __restrict__ klo) {
  int tid = threadIdx.x;
  int lane = tid & 63, wv = tid >> 6;    // 16 waves
  int slice = wv & 3;                    // o-slice (8 o each)
  int chunk = wv >> 2;                   // c-chunk (64 c each)
  int j = blockIdx.x * 64 + lane;
  int b = blockIdx.y;
  int z = blockIdx.z;
  const float* x = (z == 0) ? cross_x : front_x;
  const float* Wg = (z == 0) ? Wqf : Wkf;
  const float* bd = (z == 0) ? bq : bk;
  float* outp = (z == 0) ? qf : kf;
  unsigned short* hip_ = (z == 0) ? qhi : khi;
  unsigned short* lop_ = (z == 0) ? qlo : klo;
  int o0 = slice * 8;
  int c0 = chunk * 64;

  __shared__ __align__(16) float Wl[8192];        // [c][32] fp32, 32KB
  __shared__ float part[3 * 4 * 8 * 64];          // [chunk-1][slice][o][lane] 24KB

  for (int u = tid; u < 8192; u += 1024) Wl[u] = Wg[u];
  __syncthreads();

  const float* xb = x + (size_t)b * Cn * HWn + j;
  floatx4 a0 = (floatx4)0.0f, a1 = (floatx4)0.0f;
#pragma unroll 16
  for (int c = c0; c < c0 + 64; ++c) {
    float xv = xb[(size_t)c * HWn];
    floatx4 wa = *reinterpret_cast<const floatx4*>(&Wl[c * 32 + o0]);      // broadcast
    floatx4 wb = *reinterpret_cast<const floatx4*>(&Wl[c * 32 + o0 + 4]);
    a0 += wa * xv;
    a1 += wb * xv;
  }
  if (chunk > 0) {
    float* dst = &part[(((chunk - 1) * 4 + slice) * 8) * 64];
#pragma unroll
    for (int o = 0; o < 4; ++o) { dst[o * 64 + lane] = a0[o]; dst[(o + 4) * 64 + lane] = a1[o]; }
  }
  __syncthreads();
  if (chunk != 0) return;
#pragma unroll
  for (int q = 0; q < 3; ++q) {
    const float* src = &part[((q * 4 + slice) * 8) * 64];
#pragma unroll
    for (int o = 0; o < 4; ++o) { a0[o] += src[o * 64 + lane]; a1[o] += src[(o + 4) * 64 + lane]; }
  }
  float acc[8];
#pragma unroll
  for (int o = 0; o < 4; ++o) { acc[o] = a0[o] + bd[o0 + o]; acc[o + 4] = a1[o] + bd[o0 + 4 + o]; }

  float* op = outp + ((size_t)b * HWn + j) * C8 + o0;
  u16x8 hv, lv;
#pragma unroll
  for (int o = 0; o < 8; ++o) {
    op[o] = acc[o];
    unsigned short h = f2bf(acc[o]);
    hv[o] = h;
    lv[o] = f2bf(acc[o] - bf2f(h));
  }
  *reinterpret_cast<u16x8*>(hip_ + ((size_t)b * HWn + j) * C8 + o0) = hv;
  *reinterpret_cast<u16x8*>(lop_ + ((size_t)b * HWn + j) * C8 + o0) = lv;
}

// ---------------------------------------------------------------------------
// K2: approximate energy via split-bf16 MFMA (unchanged from R6).
// ---------------------------------------------------------------------------
__global__ __launch_bounds__(1024) void energy_approx(
    const unsigned short* __restrict__ khi, const unsigned short* __restrict__ klo,
    const unsigned short* __restrict__ qhi, const unsigned short* __restrict__ qlo,
    float* __restrict__ star, int* __restrict__ argb,
    int* __restrict__ cnt, int* __restrict__ list) {
  int b = blockIdx.y;
  int j0 = blockIdx.x * 64;
  int tid = threadIdx.x;
  int lane = tid & 63, wv = tid >> 6;   // wv 0..15
  int lm = lane & 15, lq = lane >> 4;

  __shared__ float bv1S[16][64];
  __shared__ int   bi1S[16][64];
  __shared__ float bv2S[16][64];

  bf16x8 qh[4], ql[4];
#pragma unroll
  for (int s = 0; s < 4; ++s) {
    int j = j0 + s * 16 + lm;
    qh[s] = *reinterpret_cast<const bf16x8*>(qhi + ((size_t)b * HWn + j) * 32 + lq * 8);
    ql[s] = *reinterpret_cast<const bf16x8*>(qlo + ((size_t)b * HWn + j) * 32 + lq * 8);
  }
  const unsigned short* kh_base = khi + (size_t)b * HWn * 32 + lq * 8;
  const unsigned short* kl_base = klo + (size_t)b * HWn * 32 + lq * 8;

  float b1[4], b2[4];
  int i1[4];
#pragma unroll
  for (int s = 0; s < 4; ++s) { b1[s] = -3.0e38f; b2[s] = -3.0e38f; i1[s] = 0; }

  int ibase = wv * 256;
#pragma unroll 2
  for (int it = 0; it < 16; ++it) {
    int i0 = ibase + it * 16;
    bf16x8 ah = *reinterpret_cast<const bf16x8*>(kh_base + (size_t)(i0 + lm) * 32);
    bf16x8 al = *reinterpret_cast<const bf16x8*>(kl_base + (size_t)(i0 + lm) * 32);
#pragma unroll
    for (int s = 0; s < 4; ++s) {
      floatx4 acc = (floatx4)0.0f;
      acc = __builtin_amdgcn_mfma_f32_16x16x32_bf16(ah, qh[s], acc, 0, 0, 0);
      acc = __builtin_amdgcn_mfma_f32_16x16x32_bf16(ah, ql[s], acc, 0, 0, 0);
      acc = __builtin_amdgcn_mfma_f32_16x16x32_bf16(al, qh[s], acc, 0, 0, 0);
      float m4 = fmaxf(fmaxf(acc[0], acc[1]), fmaxf(acc[2], acc[3]));
      if (m4 > b1[s]) {
        int ib = i0 + lq * 4;
#pragma unroll
        for (int r = 0; r < 4; ++r) {
          float s2 = acc[r];
          if (s2 > b1[s]) { b2[s] = b1[s]; b1[s] = s2; i1[s] = ib + r; }
          else b2[s] = fmaxf(b2[s], s2);
        }
      } else {
        b2[s] = fmaxf(b2[s], m4);
      }
    }
  }
#pragma unroll
  for (int s = 0; s < 4; ++s) {
#pragma unroll
    for (int m = 16; m <= 32; m <<= 1) {
      float ob1 = __shfl_xor(b1[s], m, 64);
      int oi1 = __shfl_xor(i1[s], m, 64);
      float ob2 = __shfl_xor(b2[s], m, 64);
      float c2;
      if (ob1 > b1[s] || (ob1 == b1[s] && oi1 < i1[s])) {
        c2 = fmaxf(b1[s], ob2);
        b1[s] = ob1; i1[s] = oi1;
      } else {
        c2 = fmaxf(ob1, b2[s]);
      }
      b2[s] = c2;
    }
    if (lq == 0) {
      bv1S[wv][s * 16 + lm] = b1[s];
      bi1S[wv][s * 16 + lm] = i1[s];
      bv2S[wv][s * 16 + lm] = b2[s];
    }
  }
  __syncthreads();
  if (tid < 64) {
    float B1 = bv1S[0][tid];
    int I1 = bi1S[0][tid];
    float B2 = bv2S[0][tid];
#pragma unroll
    for (int w = 1; w < 16; ++w) {
      float v1 = bv1S[w][tid];
      int ii = bi1S[w][tid];
      float v2 = bv2S[w][tid];
      if (v1 > B1) { B2 = fmaxf(B1, v2); B1 = v1; I1 = ii; }
      else B2 = fmaxf(B2, v1);
    }
    size_t o = (size_t)b * HWn + j0 + tid;
    star[o] = B1;
    argb[o] = I1;
    if (B1 - B2 < MARGIN) {
      int slot = atomicAdd(cnt, 1);
      list[slot] = (b << 12) | (j0 + tid);
    }
  }
}

// ---------------------------------------------------------------------------
// K3: recheck — fp64 accumulation over fp32 q,k (unchanged from R9).
// ---------------------------------------------------------------------------
__global__ __launch_bounds__(256) void recheck(
    const float* __restrict__ qf, const float* __restrict__ kf,
    const int* __restrict__ cnt, const int* __restrict__ list,
    float* __restrict__ star, int* __restrict__ argb) {
  __shared__ double bvS[4];
  __shared__ int biS[4];
  int n = cnt[0];
  int tid = threadIdx.x;
  int lane = tid & 63, wv = tid >> 6;
  for (int idx = blockIdx.x; idx < n; idx += gridDim.x) {
    int e = list[idx];
    int b = e >> 12, j = e & 4095;
    const float* qp = qf + ((size_t)b * HWn + j) * 32;
    double qj[32];
#pragma unroll
    for (int o = 0; o < 32; ++o) qj[o] = (double)qp[o];
    double best = -1.0e300;
    int bi = 1 << 30;
    for (int i = tid; i < HWn; i += 256) {
      const float* kp = kf + ((size_t)b * HWn + i) * 32;
      double s = 0.0;
#pragma unroll
      for (int o = 0; o < 32; ++o) s += (double)kp[o] * qj[o];
      if (s > best) { best = s; bi = i; }
    }
#pragma unroll
    for (int m = 1; m < 64; m <<= 1) {
      double ob = __shfl_xor(best, m, 64);
      int oi = __shfl_xor(bi, m, 64);
      if (ob > best || (ob == best && oi < bi)) { best = ob; bi = oi; }
    }
    if (lane == 0) { bvS[wv] = best; biS[wv] = bi; }
    __syncthreads();
    if (tid == 0) {
#pragma unroll
      for (int w = 1; w < 4; ++w) {
        if (bvS[w] > best || (bvS[w] == best && biS[w] < bi)) {
          best = bvS[w]; bi = biS[w];
        }
      }
      star[(size_t)b * HWn + j] = (float)best;
      argb[(size_t)b * HWn + j] = bi;
    }
    __syncthreads();
  }
}

// ---------------------------------------------------------------------------
// K4: transpose to bf16 pixel-major (unchanged).
// ---------------------------------------------------------------------------
__global__ __launch_bounds__(256) void cat_fx(
    const float* __restrict__ fx, const float* __restrict__ fxh,
    unsigned short* __restrict__ catC, unsigned short* __restrict__ xht) {
  int j0 = blockIdx.x * 64;
  int ci0 = blockIdx.y * 64;
  int b = blockIdx.z >> 1;
  int which = blockIdx.z & 1;
  int tid = threadIdx.x;
  __shared__ unsigned short tile[64][66];

  const float* src = (which == 0) ? fx : fxh;
  for (int u = tid; u < 4096; u += 256) {
    int cl = u >> 6, hw_l = u & 63;
    tile[cl][hw_l] = f2bf(src[((size_t)(b * Cn + ci0 + cl)) * HWn + j0 + hw_l]);
  }
  __syncthreads();
  if (which == 0) {
    for (int u = tid; u < 4096; u += 256) {
      int hw_l = u >> 6, cl = u & 63;
      catC[((size_t)b * ROWS + PADR + j0 + hw_l) * 512 + ci0 + cl] = tile[cl][hw_l];
    }
  } else {
    for (int u = tid; u < 4096; u += 256) {
      int hw_l = u >> 6, cl = u & 63;
      xht[((size_t)b * HWn + j0 + hw_l) * 256 + ci0 + cl] = tile[cl][hw_l];
    }
  }
}

// ---------------------------------------------------------------------------
// K5: v projection as bf16 MFMA GEMM, XOR-swizzled LDS (2-way banks = free).
// Chunk c of row r lives at LDS column c ^ ((r>>1)&3).
// ---------------------------------------------------------------------------
__global__ __launch_bounds__(256) void proj_v_mfma(
    const unsigned short* __restrict__ xht, const unsigned short* __restrict__ Wvb,
    const float* __restrict__ bv, unsigned short* __restrict__ vbf) {
  int m0 = blockIdx.x * 128;
  int o0 = blockIdx.y * 128;
  int b = blockIdx.z;
  int tid = threadIdx.x;
  int lane = tid & 63, wv = tid >> 6;
  int wm = wv >> 1, wn = wv & 1;
  int lm = lane & 15, lq = lane >> 4;

  __shared__ __align__(16) unsigned short AS[128 * 32];
  __shared__ __align__(16) unsigned short BS[128 * 32];
  __shared__ __align__(16) unsigned short TS[128 * 136];

  floatx4 acc[4][4];
#pragma unroll
  for (int im = 0; im < 4; ++im)
#pragma unroll
    for (int in = 0; in < 4; ++in) acc[im][in] = (floatx4)0.0f;

  const int srow = lane >> 2;
  const int soff = (((lane & 3) ^ ((lane >> 3) & 3)) * 8);   // swizzled source chunk
  const int sa = (lq ^ ((lm >> 1) & 3)) * 8;                 // swizzled read column
  const unsigned short* ag = Wvb + (size_t)o0 * 256;
  const unsigned short* bg = xht + ((size_t)b * HWn + m0) * 256;

  for (int kc = 0; kc < 256; kc += 32) {
    __syncthreads();
#pragma unroll
    for (int i = 0; i < 2; ++i) {
      int r0 = wv * 32 + i * 16;
      gl_lds16(ag + ((size_t)(r0 + srow)) * 256 + kc + soff, &AS[r0 * 32]);
      gl_lds16(bg + ((size_t)(r0 + srow)) * 256 + kc + soff, &BS[r0 * 32]);
    }
    __syncthreads();

    bf16x8 afr[4];
#pragma unroll
    for (int im = 0; im < 4; ++im)
      afr[im] = *reinterpret_cast<const bf16x8*>(
          &AS[(wm * 64 + im * 16 + lm) * 32 + sa]);
#pragma unroll
    for (int in = 0; in < 4; ++in) {
      bf16x8 bfr = *reinterpret_cast<const bf16x8*>(
          &BS[(wn * 64 + in * 16 + lm) * 32 + sa]);
#pragma unroll
      for (int im = 0; im < 4; ++im)
        acc[im][in] = __builtin_amdgcn_mfma_f32_16x16x32_bf16(
            afr[im], bfr, acc[im][in], 0, 0, 0);
    }
  }

  __syncthreads();
#pragma unroll
  for (int in = 0; in < 4; ++in) {
    int pl = wn * 64 + in * 16 + lm;
#pragma unroll
    for (int im = 0; im < 4; ++im) {
#pragma unroll
      for (int r = 0; r < 4; ++r) {
        int ol = wm * 64 + im * 16 + lq * 4 + r;
        TS[pl * 136 + ol] = f2bf(acc[im][in][r] + bv[o0 + ol]);
      }
    }
  }
  __syncthreads();
  for (int idx = tid; idx < 128 * 16; idx += 256) {
    int p = idx >> 4, ch = idx & 15;
    u16x8 val = *reinterpret_cast<const u16x8*>(&TS[p * 136 + ch * 8]);
    *reinterpret_cast<u16x8*>(
        &vbf[((size_t)b * HWn + m0 + p) * 256 + o0 + ch * 8]) = val;
  }
}

// ---------------------------------------------------------------------------
// K6: gather (unchanged).
// ---------------------------------------------------------------------------
__global__ __launch_bounds__(256) void gather_cat(
    const unsigned short* __restrict__ vbf, const int* __restrict__ argb,
    unsigned short* __restrict__ catC) {
  int b = blockIdx.y;
  int tid = threadIdx.x;
  if (blockIdx.x == 16) {
    for (int u = tid; u < 2 * PADR * 512; u += 256) {
      int r = u >> 9;
      int rr = (r < PADR) ? r : (HWn + r);
      catC[((size_t)b * ROWS + rr) * 512 + (u & 511)] = 0;
    }
    return;
  }
  __shared__ int ajS[256];
  int j0 = blockIdx.x * 256;
  ajS[tid] = argb[(size_t)b * HWn + j0 + tid];
  __syncthreads();
#pragma unroll 4
  for (int u = tid; u < 256 * 32; u += 256) {
    int pl = u >> 5, ch = u & 31;
    int aj = ajS[pl];
    u16x8 val = *reinterpret_cast<const u16x8*>(
        &vbf[((size_t)b * HWn + aj) * 256 + ch * 8]);
    *reinterpret_cast<u16x8*>(
        &catC[((size_t)b * ROWS + PADR + j0 + pl) * 512 + 256 + ch * 8]) = val;
  }
}

// ---------------------------------------------------------------------------
// K7: conv3x3 implicit GEMM, split-K over tap-rows, XOR-swizzled LDS
// (kills the 8-way bank conflicts: 4.7e6 -> ~0). Partials stored bf16.
// ---------------------------------------------------------------------------
__global__ __launch_bounds__(256) void conv_mfma(
    const unsigned short* __restrict__ catC, const unsigned short* __restrict__ Wfb,
    unsigned short* __restrict__ Pg) {
  int m0 = blockIdx.x * 128;
  int o0 = blockIdx.y * 128;
  int bz = blockIdx.z;
  int b = bz / 3, g = bz % 3;      // g = dy+1
  int dy = g - 1;
  int tid = threadIdx.x;
  int lane = tid & 63;
  int wv = tid >> 6;
  int wm = wv >> 1, wn = wv & 1;
  int lm = lane & 15, lq = lane >> 4;
  const bool lane_first = (lm == 0);
  const bool lane_last = (lm == 15);

  __shared__ __align__(16) unsigned short AS[3 * 128 * 32];  // [tap][o][k] 24KB
  __shared__ __align__(16) unsigned short BS[144 * 32];      // [urow][k]    9KB

  floatx4 acc[4][4];
#pragma unroll
  for (int im = 0; im < 4; ++im)
#pragma unroll
    for (int in = 0; in < 4; ++in) acc[im][in] = (floatx4)0.0f;

  const int srow = lane >> 2;
  const int soff = (((lane & 3) ^ ((lane >> 3) & 3)) * 8);   // swizzled source chunk
  const int sa = (lq ^ ((lm >> 1) & 3)) * 8;                 // A read column (rows 16-aligned+lm)
  const unsigned short* bg =
      catC + ((size_t)b * ROWS + PADR + m0 + dy * 64 - 1) * 512;
  const unsigned short* ag = Wfb + ((size_t)(g * 3) * 256 + o0) * 512;

  for (int kc = 0; kc < 512; kc += 32) {
    __syncthreads();
    if (wv < 3) {
      const unsigned short* at = ag + (size_t)wv * 256 * 512;
#pragma unroll
      for (int s = 0; s < 8; ++s)
        gl_lds16(at + ((size_t)(s * 16 + srow)) * 512 + kc + soff,
                 &AS[(wv * 128 + s * 16) * 32]);
    } else {
#pragma unroll
      for (int s = 0; s < 9; ++s)
        gl_lds16(bg + ((size_t)(s * 16 + srow)) * 512 + kc + soff,
                 &BS[(s * 16) * 32]);
    }
    __syncthreads();

#pragma unroll
    for (int t = 0; t < 3; ++t) {   // t = dx+1
      bf16x8 afr[4];
#pragma unroll
      for (int im = 0; im < 4; ++im)
        afr[im] = *reinterpret_cast<const bf16x8*>(
            &AS[(t * 128 + wm * 64 + im * 16 + lm) * 32 + sa]);
#pragma unroll
      for (int in = 0; in < 4; ++in) {
        int u = wn * 64 + in * 16 + lm + t;   // p + 1 + dx
        int sb = (lq ^ ((u >> 1) & 3)) * 8;
        u16x8 braw = *reinterpret_cast<const u16x8*>(&BS[u * 32 + sb]);
        if ((t == 0 && in == 0 && lane_first) ||
            (t == 2 && in == 3 && lane_last))
          braw = (u16x8)(unsigned short)0;
        union { u16x8 u8; bf16x8 h; } cvt; cvt.u8 = braw;
#pragma unroll
        for (int im = 0; im < 4; ++im)
          acc[im][in] = __builtin_amdgcn_mfma_f32_16x16x32_bf16(
              afr[im], cvt.h, acc[im][in], 0, 0, 0);
      }
    }
  }

  unsigned short* P = Pg + ((size_t)(g * Bn + b) * Cn) * HWn;
#pragma unroll
  for (int in = 0; in < 4; ++in) {
    int p = m0 + wn * 64 + in * 16 + lm;
#pragma unroll
    for (int im = 0; im < 4; ++im) {
      int ob = o0 + wm * 64 + im * 16 + lq * 4;
#pragma unroll
      for (int r = 0; r < 4; ++r)
        P[(size_t)(ob + r) * HWn + p] = f2bf(acc[im][in][r]);
    }
  }
}

// ---------------------------------------------------------------------------
// K8: combine: out = fx + (P0+P1+P2 + bf)*S over bf16 partials, 8 elem/thread.
// ---------------------------------------------------------------------------
__global__ __launch_bounds__(256) void combine(
    const unsigned short* __restrict__ Pg, const float* __restrict__ fx,
    const float* __restrict__ bf, const float* __restrict__ star,
    float* __restrict__ out) {
  size_t e = ((size_t)blockIdx.x * 256 + threadIdx.x) * 8;
  int p = (int)(e & 4095);
  int bo = (int)(e >> 12);
  int o = bo & 255, b = bo >> 8;
  const size_t gs = (size_t)Bn * Cn * HWn;
  u16x8 q0 = *reinterpret_cast<const u16x8*>(Pg + e);
  u16x8 q1 = *reinterpret_cast<const u16x8*>(Pg + gs + e);
  u16x8 q2 = *reinterpret_cast<const u16x8*>(Pg + 2 * gs + e);
  float bias = bf[o];
  const float* sp = star + (size_t)b * HWn + p;
  const float* fp = fx + e;
  float* op = out + e;
#pragma unroll
  for (int h = 0; h < 2; ++h) {
    floatx4 s = *reinterpret_cast<const floatx4*>(sp + h * 4);
    floatx4 f = *reinterpret_cast<const floatx4*>(fp + h * 4);
    floatx4 r;
#pragma unroll
    for (int i = 0; i < 4; ++i) {
      int k = h * 4 + i;
      float a = bf2f(q0[k]) + bf2f(q1[k]) + bf2f(q2[k]);
      r[i] = f[i] + (a + bias) * s[i];
    }
    *reinterpret_cast<floatx4*>(op + h * 4) = r;
  }
}

// ---------------------------------------------------------------------------
extern "C" void kernel_launch(void* const* d_in, const int* in_sizes, int n_in,
                              void* d_out, int out_size, void* d_ws, size_t ws_size,
                              hipStream_t stream) {
  const float* front_x   = (const float*)d_in[0];
  const float* cross_x   = (const float*)d_in[1];
  const float* front_hat = (const float*)d_in[2];
  const float* Wq = (const float*)d_in[3];
  const float* bq = (const float*)d_in[4];
  const float* Wk = (const float*)d_in[5];
  const float* bk = (const float*)d_in[6];
  const float* Wv = (const float*)d_in[7];
  const float* bv = (const float*)d_in[8];
  const float* Wf = (const float*)d_in[9];
  const float* bf = (const float*)d_in[10];
  float* out = (float*)d_out;

  char* ws = (char*)d_ws;
  size_t off = 0;
  auto alloc = [&](size_t bytes) -> void* {
    void* p = (void*)(ws + off);
    off += (bytes + 255) & ~(size_t)255;
    return p;
  };
  float* Wqf = (float*)alloc(8192 * sizeof(float));
  float* Wkf = (float*)alloc(8192 * sizeof(float));
  unsigned short* Wvb = (unsigned short*)alloc(65536 * sizeof(unsigned short));
  unsigned short* Wfb = (unsigned short*)alloc((size_t)9 * 256 * 512 * sizeof(unsigned short));
  float* qf  = (float*)alloc((size_t)Bn * HWn * C8 * sizeof(float));
  float* kf  = (float*)alloc((size_t)Bn * HWn * C8 * sizeof(float));
  unsigned short* qhi = (unsigned short*)alloc((size_t)Bn * HWn * C8 * 2);
  unsigned short* qlo = (unsigned short*)alloc((size_t)Bn * HWn * C8 * 2);
  unsigned short* khi = (unsigned short*)alloc((size_t)Bn * HWn * C8 * 2);
  unsigned short* klo = (unsigned short*)alloc((size_t)Bn * HWn * C8 * 2);
  float*  star = (float*)alloc((size_t)Bn * HWn * sizeof(float));
  int*    argb = (int*)alloc((size_t)Bn * HWn * sizeof(int));
  int*    cnt  = (int*)alloc(256);
  int*    list = (int*)alloc((size_t)Bn * HWn * sizeof(int));
  unsigned short* xht = (unsigned short*)alloc((size_t)Bn * HWn * 256 * 2);
  unsigned short* vbf = (unsigned short*)alloc((size_t)Bn * HWn * 256 * 2);
  unsigned short* catC = (unsigned short*)alloc((size_t)Bn * ROWS * 512 * sizeof(unsigned short));
  unsigned short* Pg = (unsigned short*)alloc((size_t)3 * Bn * Cn * HWn * 2);  // 25 MB bf16

  prep_w<<<dim3((9 * 256 * 512 + 255) / 256), dim3(256), 0, stream>>>(
      Wq, Wk, Wv, Wf, Wqf, Wkf, Wvb, Wfb, cnt);

  proj_qk<<<dim3(HWn / 64, Bn, 2), dim3(1024), 0, stream>>>(
      cross_x, front_x, Wqf, bq, Wkf, bk, qf, kf, qhi, qlo, khi, klo);

  energy_approx<<<dim3(HWn / 64, Bn), dim3(1024), 0, stream>>>(
      khi, klo, qhi, qlo, star, argb, cnt, list);

  recheck<<<dim3(256), dim3(256), 0, stream>>>(qf, kf, cnt, list, star, argb);

  cat_fx<<<dim3(HWn / 64, Cn / 64, Bn * 2), dim3(256), 0, stream>>>(
      front_x, front_hat, catC, xht);

  proj_v_mfma<<<dim3(HWn / 128, Cn / 128, Bn), dim3(256), 0, stream>>>(
      xht, Wvb, bv, vbf);

  gather_cat<<<dim3(HWn / 256 + 1, Bn), dim3(256), 0, stream>>>(vbf, argb, catC);

  conv_mfma<<<dim3(HWn / 128, Cn / 128, Bn * 3), dim3(256), 0, stream>>>(
      catC, Wfb, Pg);

  combine<<<dim3((Bn * Cn * HWn / 8) / 256), dim3(256), 0, stream>>>(
      Pg, front_x, bf, star, out);
}